// Round 10
// baseline (446.428 us; speedup 1.0000x reference)
//
#include <hip/hip_runtime.h>
#include <math.h>

// Problem constants
#define BB 4
#define NN 8192
#define CC 64
#define KK 16
#define HH 64
#define NPTS (BB*NN)   // 32768
#define EPSBN 1e-5f
#define CAP 64         // candidate buffer per query (fp64 refine picks 16)
#define NCELL 4096     // 16^3 Morton cells
#define NCHUNK 32      // 256-point chunks per batch

// ---------------- ws layout (float offsets) ----------------
#define OFF_XYZW  0
#define OFF_PW1AT 131072
#define OFF_PW1BT 135168
#define OFF_PWVAT 139264
#define OFF_PWOT  143360
#define OFF_RELW  147456
#define OFF_STATS 147840
#define OFF_IDX   148224      // idx: 32768*16 ints (SORTED-space neighbor ids)
#define OFF_PIP   672512      // pip: 32768*CAP ints (dead after k_refine)
#define OFF_OUTV  672512      // OUTV aliases PIP: [32768][64] sorted attention output
#define OFF_SX4   2769664     // sorted xyzw [4][8192] float4
#define OFF_SID   2900736     // sorted->orig ids [4][8192] int
#define OFF_HIST  2933504     // [4][4096] int
#define OFF_BB    2949888     // bbmin[128] f4 + bbmax[128] f4
#define OFF_RANK  2950912     // orig->sorted rank [4][8192] int
#define OFF_PH    2983680     // k_hv block partials [2048][256]
#define OFF_PO    3507968     // k_o block partials [512][128]
#define OFF_KC    3573504     // per-query candidate count [32768] int
#define OFF_F1    4866816     // SORTED layout (dead after k_attn)
#define OFF_OPRE  4866816     // OPRE aliases F1: [32768][64] original layout
#define OFF_F2    6963968     // SORTED layout
#define OFF_FV    9061120     // SORTED layout

__device__ __forceinline__ int morton_cell(float x, float y, float z) {
    int cx = (int)floorf((x + 4.f) * 2.f);
    int cy = (int)floorf((y + 4.f) * 2.f);
    int cz = (int)floorf((z + 4.f) * 2.f);
    cx = cx < 0 ? 0 : (cx > 15 ? 15 : cx);
    cy = cy < 0 ? 0 : (cy > 15 ? 15 : cy);
    cz = cz < 0 ? 0 : (cz > 15 ? 15 : cz);
    int ex = (cx & 1) | ((cx & 2) << 2) | ((cx & 4) << 4) | ((cx & 8) << 6);
    int ey = (cy & 1) | ((cy & 2) << 2) | ((cy & 4) << 4) | ((cy & 8) << 6);
    int ez = (cz & 1) | ((cz & 2) << 2) | ((cz & 4) << 4) | ((cz & 8) << 6);
    return ex | (ey << 1) | (ez << 2);
}

__device__ __forceinline__ float distf(float4 me, float jx, float jy, float jz, float jw) {
    float dot = fmaf(me.z, jz, fmaf(me.y, jy, me.x * jx));
    return fmaf(-2.f, dot, me.w) + jw;
}

__device__ __forceinline__ float mind2(float4 me, float4 bmin, float4 bmax) {
    float dx = fmaxf(fmaxf(bmin.x - me.x, me.x - bmax.x), 0.f);
    float dy = fmaxf(fmaxf(bmin.y - me.y, me.y - bmax.y), 0.f);
    float dz = fmaxf(fmaxf(bmin.z - me.z, me.z - bmax.z), 0.f);
    return fmaf(dx, dx, fmaf(dy, dy, dz * dz));
}

__device__ __forceinline__ int mbcnt64(unsigned long long m) {
    return __builtin_amdgcn_mbcnt_hi((unsigned int)(m >> 32),
           __builtin_amdgcn_mbcnt_lo((unsigned int)m, 0));
}

__global__ __launch_bounds__(256) void k_zero(int* __restrict__ hist) {
    int t = threadIdx.x;
    for (int i = t; i < BB * NCELL; i += 256) hist[i] = 0;
}

__global__ __launch_bounds__(256) void k_prep(
    const float* __restrict__ xyz, const float* __restrict__ W1,
    const float* __restrict__ Wv, const float* __restrict__ Wo,
    float* __restrict__ xyzw, int* __restrict__ hist,
    float* __restrict__ pw1aT, float* __restrict__ pw1bT,
    float* __restrict__ pwvaT, float* __restrict__ pwoT, float* __restrict__ relw,
    float* __restrict__ stats)
{
    int t = threadIdx.x;
    int bid = blockIdx.x;
    if (bid < 128) {
        int pt = bid * 256 + t;
        int b = pt >> 13, n = pt & 8191;
        const float* xb = xyz + (size_t)b * 3 * NN;
        float x = xb[n], y = xb[NN + n], z = xb[2 * NN + n];
        float sq = __fadd_rn(__fadd_rn(__fmul_rn(x, x), __fmul_rn(y, y)), __fmul_rn(z, z));
        ((float4*)xyzw)[pt] = make_float4(x, y, z, sq);
        atomicAdd(&hist[b * NCELL + morton_cell(x, y, z)], 1);
    } else {
        for (int e = t; e < 4096; e += 256) {
            int c = e >> 6, o = e & 63;
            pw1aT[e] = W1[o * 131 + c];
            pw1bT[e] = W1[o * 131 + 64 + c];
            pwvaT[e] = Wv[o * 67 + c];
            pwoT[e]  = Wo[o * 64 + c];
        }
        for (int e = t; e < 384; e += 256) {
            int d = e >> 6, o = e & 63;
            relw[e] = (d < 3) ? W1[o * 131 + 128 + d] : Wv[o * 67 + 64 + (d - 3)];
            stats[e] = 0.0f;
        }
    }
}

// Exclusive scan of per-batch 4096-bin histogram (in place), one block per batch.
__global__ __launch_bounds__(256) void k_scan(int* __restrict__ hist) {
    __shared__ int part[256];
    int b = blockIdx.x, t = threadIdx.x;
    int* h = hist + b * NCELL;
    int loc[16]; int s = 0;
#pragma unroll
    for (int i = 0; i < 16; i++) { loc[i] = h[t * 16 + i]; s += loc[i]; }
    part[t] = s;
    __syncthreads();
    for (int off = 1; off < 256; off <<= 1) {
        int v = (t >= off) ? part[t - off] : 0;
        __syncthreads();
        part[t] += v;
        __syncthreads();
    }
    int run = (t > 0) ? part[t - 1] : 0;
#pragma unroll
    for (int i = 0; i < 16; i++) { int c = loc[i]; h[t * 16 + i] = run; run += c; }
}

__global__ __launch_bounds__(256) void k_scatter(
    const float4* __restrict__ xyzw, int* __restrict__ off,
    float4* __restrict__ sx4, int* __restrict__ sid, int* __restrict__ rank)
{
    int pt = blockIdx.x * 256 + threadIdx.x;
    int b = pt >> 13, n = pt & 8191;
    float4 p = xyzw[pt];
    int cell = morton_cell(p.x, p.y, p.z);
    int dst = atomicAdd(&off[b * NCELL + cell], 1);
    sx4[(b << 13) + dst] = p;
    sid[(b << 13) + dst] = n;
    rank[pt] = dst;
}

// Per-chunk bbox over 256 sorted points. block = chunk (0..127 global).
__global__ __launch_bounds__(256) void k_bbox(
    const float4* __restrict__ sx4, float4* __restrict__ bbmin, float4* __restrict__ bbmax)
{
    __shared__ float smn[4][3], smx[4][3];
    int ch = blockIdx.x, t = threadIdx.x, lane = t & 63, wl = t >> 6;
    float4 p = sx4[ch * 256 + t];
    float mnx = p.x, mny = p.y, mnz = p.z, mxx = p.x, mxy = p.y, mxz = p.z;
#pragma unroll
    for (int o = 32; o >= 1; o >>= 1) {
        mnx = fminf(mnx, __shfl_xor(mnx, o, 64)); mxx = fmaxf(mxx, __shfl_xor(mxx, o, 64));
        mny = fminf(mny, __shfl_xor(mny, o, 64)); mxy = fmaxf(mxy, __shfl_xor(mxy, o, 64));
        mnz = fminf(mnz, __shfl_xor(mnz, o, 64)); mxz = fmaxf(mxz, __shfl_xor(mxz, o, 64));
    }
    if (lane == 0) { smn[wl][0]=mnx; smn[wl][1]=mny; smn[wl][2]=mnz;
                     smx[wl][0]=mxx; smx[wl][1]=mxy; smx[wl][2]=mxz; }
    __syncthreads();
    if (t == 0) {
        float a0=smn[0][0], a1=smn[0][1], a2=smn[0][2];
        float b0=smx[0][0], b1=smx[0][1], b2=smx[0][2];
        for (int w = 1; w < 4; w++) {
            a0=fminf(a0,smn[w][0]); a1=fminf(a1,smn[w][1]); a2=fminf(a2,smn[w][2]);
            b0=fmaxf(b0,smx[w][0]); b1=fmaxf(b1,smx[w][1]); b2=fmaxf(b2,smx[w][2]);
        }
        bbmin[ch] = make_float4(a0,a1,a2,0.f);
        bbmax[ch] = make_float4(b0,b1,b2,0.f);
    }
}

// KNN candidate collection: window sort gives tau = 32nd-best; then ALL points
// with d <= tau (+margin) are appended (ballot+mbcnt prefix) -- no list
// maintenance, no LDS, no barriers. Rare overflow (>CAP) falls back to the
// verified sorted-insert top-32 path.
__global__ __launch_bounds__(256) void k_knn(
    const float4* __restrict__ sx4,
    const float4* __restrict__ bbmin, const float4* __restrict__ bbmax,
    int* __restrict__ pip, int* __restrict__ kc)
{
    int t = threadIdx.x, lane = t & 63, wl = t >> 6;
    int gq = blockIdx.x * 4 + wl;
    int b = __builtin_amdgcn_readfirstlane(gq >> 13);
    int qs = gq & 8191;
    const float4* sb = sx4 + ((size_t)b << 13);
    float4 me = sb[qs];                       // wave-uniform
    const float INF = 3.402823466e38f;

    // phase 1: bitonic-sort the 64-point positional window (warm tau)
    int ws0 = qs - 32; ws0 = ws0 < 0 ? 0 : (ws0 > (NN - 64) ? (NN - 64) : ws0);
    float4 cp = sb[ws0 + lane];
    int cid = ws0 + lane;                     // sorted-space id
    float d = distf(me, cp.x, cp.y, cp.z, cp.w);
#pragma unroll
    for (int k2 = 2; k2 <= 64; k2 <<= 1) {
#pragma unroll
        for (int j2 = k2 >> 1; j2 >= 1; j2 >>= 1) {
            float od = __shfl_xor(d, j2, 64);
            int   oi = __shfl_xor(cid, j2, 64);
            bool up = ((lane & k2) == 0);
            bool lower = ((lane & j2) == 0);
            bool wantMin = (lower == up);
            bool to = wantMin ? (od < d) : (od > d);
            d = to ? od : d; cid = to ? oi : cid;
        }
    }
    bool lt32 = (lane < 32);
    float tau = __int_as_float(__builtin_amdgcn_readlane(__float_as_int(d), 31));
    float tauA = tau * 1.0001f + 1e-5f;
    int* row = pip + (size_t)gq * CAP;

    // seed buffer with window entries <= tauA (sorted lanes; no dups vs scan)
    {
        bool hit = lt32 && (d <= tauA);
        unsigned long long hm = __ballot(hit);
        if (hit) row[mbcnt64(hm)] = cid;
        int cnt = __popcll(hm);

        // phase 2a: lane-distributed chunk mask
        float md = INF;
        if (lt32) md = mind2(me, bbmin[b * NCHUNK + lane], bbmax[b * NCHUNK + lane]);
        unsigned int bm = (unsigned int)__ballot(md <= tauA);

        // phase 2b: per-wave chunk scan, direct global loads, prefix-append
        unsigned int bms = bm;
        while (bms) {
            int c = __builtin_ctz(bms); bms &= bms - 1;
#pragma unroll
            for (int s = 0; s < 4; s++) {
                int pos = c * 256 + s * 64 + lane;
                float4 p = sb[pos];
                float dd = distf(me, p.x, p.y, p.z, p.w);
                bool inwin = (pos >= ws0) && (pos < ws0 + 64);
                bool hit2 = (dd <= tauA) && !inwin;
                unsigned long long m2 = __ballot(hit2);
                if (hit2) {
                    int slot = cnt + mbcnt64(m2);
                    if (slot < CAP) row[slot] = pos;
                }
                cnt += __popcll(m2);
            }
        }

        if (cnt <= CAP) {
            if (lane == 0) kc[gq] = cnt;
            return;
        }
    }

    // ---- rare fallback: verified sorted-insert top-32 (window-seeded) ----
    {
        float val = lt32 ? d : INF;
        int vid = cid;
        float tau2 = __int_as_float(__builtin_amdgcn_readlane(__float_as_int(val), 31));
        float md = INF;
        if (lt32) md = mind2(me, bbmin[b * NCHUNK + lane], bbmax[b * NCHUNK + lane]);
        unsigned int bm = (unsigned int)__ballot(md <= tau2 * 1.0001f + 1e-5f);
        while (bm) {
            int c = __builtin_ctz(bm); bm &= bm - 1;
#pragma unroll 2
            for (int s = 0; s < 4; s++) {
                int pos = c * 256 + s * 64 + lane;
                float4 p = sb[pos];
                float dd = distf(me, p.x, p.y, p.z, p.w);
                bool inwin = (pos >= ws0) && (pos < ws0 + 64);
                dd = inwin ? INF : dd;
                unsigned long long m = __ballot(dd < tau2);
                while (m) {
                    int hl = __builtin_ctzll(m); m &= m - 1;
                    float dn = __int_as_float(
                        __builtin_amdgcn_readlane(__float_as_int(dd), hl));
                    int jn = c * 256 + s * 64 + hl;
                    unsigned long long bl = __ballot(val < dn);
                    int pos2 = __popcll(bl);
                    float sv = __shfl_up(val, 1, 64);
                    int   sj = __shfl_up(vid, 1, 64);
                    float nv = (lane > pos2) ? sv : val; nv = (lane == pos2) ? dn : nv;
                    int   nj = (lane > pos2) ? sj : vid; nj = (lane == pos2) ? jn : nj;
                    val = lt32 ? nv : val;
                    vid = lt32 ? nj : vid;
                    tau2 = __int_as_float(__builtin_amdgcn_readlane(__float_as_int(val), 31));
                }
            }
        }
        if (lt32) row[lane] = vid;
        if (lane == 0) kc[gq] = 32;
    }
}

// Exact refinement in SORTED space: fp64 distances for kc[gq] candidates,
// top-16 by (d, ORIGINAL index). Outputs sorted-space ids.
__global__ __launch_bounds__(256) void k_refine(
    const float4* __restrict__ sx4, const int* __restrict__ sid,
    const int* __restrict__ pip, const int* __restrict__ kc, int* __restrict__ idx)
{
    int gq = blockIdx.x * 256 + threadIdx.x;
    int b = gq >> 13;
    const float4* sb = sx4 + ((size_t)b << 13);
    const int* ib = sid + ((size_t)b << 13);
    float4 mef = sb[gq & 8191];
    double mx = (double)mef.x, my = (double)mef.y, mz = (double)mef.z;
    double msq = (mx * mx + my * my) + mz * mz;
    int cnt = kc[gq];
    double bd[16]; int bi[16]; int bo[16];
#pragma unroll
    for (int s = 0; s < 16; s++) { bd[s] = 1e300; bi[s] = 0; bo[s] = 0x7fffffff; }
    for (int c = 0; c < cnt; c++) {
        int j = pip[(size_t)gq * CAP + c];
        float4 cj = sb[j];
        int oj = ib[j];
        double jx = (double)cj.x, jy = (double)cj.y, jz = (double)cj.z;
        double dot = (mx * jx + my * jy) + mz * jz;
        double sqj = (jx * jx + jy * jy) + jz * jz;
        double dd = (-2.0 * dot + msq) + sqj;
        if (dd < bd[15] || (dd == bd[15] && oj < bo[15])) {
            double pd_ = dd; int pi_ = j; int po_ = oj;
#pragma unroll
            for (int s = 15; s >= 1; s--) {
                bool cc = (pd_ < bd[s - 1]) || (pd_ == bd[s - 1] && po_ < bo[s - 1]);
                double nd = cc ? bd[s - 1] : pd_;  int ni = cc ? bi[s - 1] : pi_;  int no = cc ? bo[s - 1] : po_;
                double npd = cc ? pd_ : bd[s - 1]; int npi = cc ? pi_ : bi[s - 1]; int npo = cc ? po_ : bo[s - 1];
                bd[s] = nd; bi[s] = ni; bo[s] = no; pd_ = npd; pi_ = npi; po_ = npo;
            }
            bd[0] = pd_; bi[0] = pi_; bo[0] = po_;
        }
    }
#pragma unroll
    for (int s = 0; s < 16; s++) idx[(size_t)gq * 16 + s] = bi[s];
}

// Per-point GEMVs, output scattered to SORTED layout via rank.
__global__ __launch_bounds__(256) void k_F(
    const float* __restrict__ feats, const float* __restrict__ b1, const float* __restrict__ bv,
    const float* __restrict__ pw1aT, const float* __restrict__ pw1bT, const float* __restrict__ pwvaT,
    const int* __restrict__ rank,
    float* __restrict__ F1, float* __restrict__ F2, float* __restrict__ FV)
{
    int t = threadIdx.x;
    int lane = t & 63;
    int wave = t >> 6;
    int pt0 = blockIdx.x * 64 + wave * 16;
    int b   = __builtin_amdgcn_readfirstlane(pt0 >> 13);
    int n0  = __builtin_amdgcn_readfirstlane(pt0 & 8191);
    const float* fb = feats + (size_t)b * CC * NN;
    float accA[16], accB[16], accV[16];
    float bb1 = b1[lane], bbv = bv[lane];
#pragma unroll
    for (int p = 0; p < 16; p++) { accA[p] = bb1; accB[p] = 0.f; accV[p] = bbv; }
    for (int c = 0; c < 64; c++) {
        float wA = pw1aT[c * 64 + lane];
        float wB = pw1bT[c * 64 + lane];
        float wV = pwvaT[c * 64 + lane];
        const float* fr = fb + (size_t)c * NN + n0;
#pragma unroll
        for (int p = 0; p < 16; p++) {
            float f = fr[p];
            accA[p] = fmaf(wA, f, accA[p]);
            accB[p] = fmaf(wB, f, accB[p]);
            accV[p] = fmaf(wV, f, accV[p]);
        }
    }
#pragma unroll
    for (int p = 0; p < 16; p++) {
        int dst = (b << 13) + rank[pt0 + p];     // wave-uniform scalar
        F1[(size_t)dst * 64 + lane] = accA[p];
        F2[(size_t)dst * 64 + lane] = accB[p];
        FV[(size_t)dst * 64 + lane] = accV[p];
    }
}

// BN stats pass. XCD-swizzled; block partials to PH (NO contended atomics).
__global__ __launch_bounds__(256) void k_hv(
    const float4* __restrict__ sx4, const int* __restrict__ idx,
    const float* __restrict__ F1, const float* __restrict__ F2, const float* __restrict__ FV,
    const float* __restrict__ relw, float* __restrict__ ph)
{
    __shared__ float red[4][4][64];
    int t = threadIdx.x;
    int lane = t & 63;
    int wl = t >> 6;
    int bx = blockIdx.x;                       // 2048 blocks
    int vb = (bx & 7) * 256 + (bx >> 3);       // XCD-aware swizzle
    float rw0 = relw[0 * 64 + lane], rw1 = relw[1 * 64 + lane], rw2 = relw[2 * 64 + lane];
    float rw3 = relw[3 * 64 + lane], rw4 = relw[4 * 64 + lane], rw5 = relw[5 * 64 + lane];
    float sh = 0.f, sh2 = 0.f, sv = 0.f, sv2 = 0.f;
    for (int i = 0; i < 4; i++) {
        int gq = __builtin_amdgcn_readfirstlane(vb * 16 + wl * 4 + i);  // contiguous
        int b = gq >> 13;
        const float4* sb = sx4 + ((size_t)b << 13);
        float4 me = sb[gq & 8191];
        float F1v = F1[(size_t)gq * 64 + lane];
        const int* ip = idx + (size_t)gq * 16;
#pragma unroll
        for (int kb = 0; kb < 2; kb++) {
            float4 cjA[8]; float f2A[8], fvA[8];
#pragma unroll
            for (int j = 0; j < 8; j++) {
                int gl = ip[kb * 8 + j];
                cjA[j] = sb[gl];
                size_t go = (size_t)((b << 13) + gl) * 64 + lane;
                f2A[j] = F2[go];
                fvA[j] = FV[go];
            }
#pragma unroll
            for (int j = 0; j < 8; j++) {
                float rx = cjA[j].x - me.x, ry = cjA[j].y - me.y, rz = cjA[j].z - me.z;
                float h = F1v + f2A[j];
                h = fmaf(rw0, rx, h); h = fmaf(rw1, ry, h); h = fmaf(rw2, rz, h);
                float v = fvA[j];
                v = fmaf(rw3, rx, v); v = fmaf(rw4, ry, v); v = fmaf(rw5, rz, v);
                sh += h; sh2 = fmaf(h, h, sh2);
                sv += v; sv2 = fmaf(v, v, sv2);
            }
        }
    }
    red[0][wl][lane] = sh; red[1][wl][lane] = sh2;
    red[2][wl][lane] = sv; red[3][wl][lane] = sv2;
    __syncthreads();
    float s = red[wl][0][lane] + red[wl][1][lane] + red[wl][2][lane] + red[wl][3][lane];
    ph[(size_t)bx * 256 + wl * 64 + lane] = s;     // plain store, no contention
}

// Reduce PH -> stats[0..255]. 32 blocks x 64 rows each; light atomics (32/addr).
__global__ __launch_bounds__(256) void k_red1(
    const float* __restrict__ ph, float* __restrict__ stats)
{
    int t = threadIdx.x, p = blockIdx.x;
    float acc = 0.f;
    for (int i = 0; i < 64; i++)
        acc += ph[(size_t)(p * 64 + i) * 256 + t];
    atomicAdd(&stats[t], acc);
}

// Attention in SORTED space, XCD-swizzled. Barrier-free, atomic-free, LDS-free.
__global__ __launch_bounds__(256) void k_attn(
    const float4* __restrict__ sx4,
    const int* __restrict__ idx,
    const float* __restrict__ F1, const float* __restrict__ F2, const float* __restrict__ FV,
    const float* __restrict__ relw, const float* __restrict__ stats,
    const float* __restrict__ g1, const float* __restrict__ be1,
    const float* __restrict__ W2, const float* __restrict__ b2,
    const float* __restrict__ gv, const float* __restrict__ bev,
    float* __restrict__ outv)
{
    int t = threadIdx.x;
    int lane = t & 63;
    int wl = t >> 6;
    int bx = blockIdx.x;                      // 8192 blocks
    int vb = (bx & 7) * 1024 + (bx >> 3);     // XCD-aware swizzle
    int gq = vb * 4 + wl;                     // sorted-global query
    const float invM = 1.f / 524288.f;
    float hm = stats[lane] * invM, hq = stats[64 + lane] * invM;
    float s1 = g1[lane] * rsqrtf(hq - hm * hm + EPSBN);
    float t1 = be1[lane] - s1 * hm;
    float vm = stats[128 + lane] * invM, vq = stats[192 + lane] * invM;
    float sv = gv[lane] * rsqrtf(vq - vm * vm + EPSBN);
    float tv = bev[lane] - sv * vm;
    float rw0 = relw[0 * 64 + lane], rw1 = relw[1 * 64 + lane], rw2 = relw[2 * 64 + lane];
    float rw3 = relw[3 * 64 + lane], rw4 = relw[4 * 64 + lane], rw5 = relw[5 * 64 + lane];
    float w2v = W2[lane];
    float b2v = b2[0];

    int b = __builtin_amdgcn_readfirstlane(gq >> 13);
    const float4* sb = sx4 + ((size_t)b << 13);
    float4 me = sb[gq & 8191];
    float F1v = F1[(size_t)gq * 64 + lane];
    const int* ip = idx + (size_t)gq * 16;
    float ek[16], vk[16];
#pragma unroll
    for (int kb = 0; kb < 2; kb++) {
        float4 cjA[8]; float f2A[8], fvA[8];
#pragma unroll
        for (int j = 0; j < 8; j++) {
            int gl = ip[kb * 8 + j];
            cjA[j] = sb[gl];
            size_t go = (size_t)((b << 13) + gl) * 64 + lane;
            f2A[j] = F2[go];
            fvA[j] = FV[go];
        }
#pragma unroll
        for (int j = 0; j < 8; j++) {
            int k = kb * 8 + j;
            float rx = cjA[j].x - me.x, ry = cjA[j].y - me.y, rz = cjA[j].z - me.z;
            float h = F1v + f2A[j];
            h = fmaf(rw0, rx, h); h = fmaf(rw1, ry, h); h = fmaf(rw2, rz, h);
            float a = fmaxf(fmaf(s1, h, t1), 0.f);
            float v = fvA[j];
            v = fmaf(rw3, rx, v); v = fmaf(rw4, ry, v); v = fmaf(rw5, rz, v);
            vk[k] = fmaxf(fmaf(sv, v, tv), 0.f);
            float lg = w2v * a;
#pragma unroll
            for (int off = 32; off >= 1; off >>= 1) lg += __shfl_xor(lg, off, 64);
            ek[k] = lg + b2v;
        }
    }
    float mx = ek[0];
#pragma unroll
    for (int k = 1; k < 16; k++) mx = fmaxf(mx, ek[k]);
    float ssum = 0.f;
#pragma unroll
    for (int k = 0; k < 16; k++) { float e = __expf(ek[k] - mx); ek[k] = e; ssum += e; }
    float acc = 0.f;
#pragma unroll
    for (int k = 0; k < 16; k++) acc = fmaf(ek[k], vk[k], acc);
    outv[(size_t)gq * 64 + lane] = acc / ssum;
}

// Wo matvec + o-stats: out rows (sorted) -> o_pre rows (ORIGINAL layout) + PO partials.
__global__ __launch_bounds__(256) void k_o(
    const float* __restrict__ outv, const float* __restrict__ pwoT,
    const float* __restrict__ bo, const int* __restrict__ sid,
    float* __restrict__ opre, float* __restrict__ po)
{
    __shared__ float red[2][4][64];
    int t = threadIdx.x;
    int lane = t & 63;
    int wl = t >> 6;
    int gq0 = blockIdx.x * 64 + wl * 16;       // 16 sorted points per wave
    int b = __builtin_amdgcn_readfirstlane(gq0 >> 13);
    float acc[16];
    float bov = bo[lane];
#pragma unroll
    for (int p = 0; p < 16; p++) acc[p] = bov;
    for (int c = 0; c < 64; c++) {
        float w = pwoT[c * 64 + lane];
        const float* orow = outv + (size_t)gq0 * 64 + c;
#pragma unroll
        for (int p = 0; p < 16; p++)
            acc[p] = fmaf(w, orow[p * 64], acc[p]);
    }
    float so = 0.f, so2 = 0.f;
#pragma unroll
    for (int p = 0; p < 16; p++) {
        int orig = (b << 13) + sid[gq0 + p];   // wave-uniform scalar
        opre[(size_t)orig * 64 + lane] = acc[p];
        so += acc[p]; so2 = fmaf(acc[p], acc[p], so2);
    }
    red[0][wl][lane] = so; red[1][wl][lane] = so2;
    __syncthreads();
    if (wl < 2) {
        float s = red[wl][0][lane] + red[wl][1][lane] + red[wl][2][lane] + red[wl][3][lane];
        po[(size_t)blockIdx.x * 128 + wl * 64 + lane] = s;
    }
}

// Reduce PO -> stats[256..383]. 8 blocks x 64 rows; light atomics.
__global__ __launch_bounds__(256) void k_red2(
    const float* __restrict__ po, float* __restrict__ stats)
{
    int t = threadIdx.x, p = blockIdx.x;
    if (t < 128) {
        float acc = 0.f;
        for (int i = 0; i < 64; i++)
            acc += po[(size_t)(p * 64 + i) * 128 + t];
        atomicAdd(&stats[256 + t], acc);
    }
}

// Final: BN(o)+relu + residual feats, transpose [B,N,C]->[B,C,N]
__global__ __launch_bounds__(256) void k_final(
    const float* __restrict__ opre, const float* __restrict__ stats,
    const float* __restrict__ go, const float* __restrict__ beo,
    const float* __restrict__ feats, float* __restrict__ out)
{
    __shared__ float tile[64][65];
    int t = threadIdx.x;
    int blk = blockIdx.x;
    int b = blk >> 7, n0 = (blk & 127) << 6;
#pragma unroll
    for (int i = 0; i < 16; i++) {
        int e = t + i * 256;
        int r = e >> 6, c = e & 63;
        tile[r][c] = opre[((size_t)((b << 13) + n0 + r)) * 64 + c];
    }
    __syncthreads();
    const float invM = 1.f / 32768.f;
    int lane = t & 63, wv = t >> 6;
#pragma unroll
    for (int i = 0; i < 16; i++) {
        int c = wv * 16 + i;
        float om = stats[256 + c] * invM, oq = stats[320 + c] * invM;
        float so = go[c] * rsqrtf(oq - om * om + EPSBN);
        float to = beo[c] - so * om;
        float val = fmaxf(fmaf(so, tile[lane][c], to), 0.f);
        size_t oix = ((size_t)b * 64 + c) * NN + n0 + lane;
        out[oix] = val + feats[oix];
    }
}

extern "C" void kernel_launch(void* const* d_in, const int* in_sizes, int n_in,
                              void* d_out, int out_size, void* d_ws, size_t ws_size,
                              hipStream_t stream)
{
    const float* xyz  = (const float*)d_in[0];
    const float* feats= (const float*)d_in[1];
    const float* W1   = (const float*)d_in[2];
    const float* b1   = (const float*)d_in[3];
    const float* g1   = (const float*)d_in[4];
    const float* be1  = (const float*)d_in[5];
    const float* W2   = (const float*)d_in[6];
    const float* b2   = (const float*)d_in[7];
    const float* Wv   = (const float*)d_in[8];
    const float* bv   = (const float*)d_in[9];
    const float* gv   = (const float*)d_in[10];
    const float* bev  = (const float*)d_in[11];
    const float* Wo   = (const float*)d_in[12];
    const float* bo   = (const float*)d_in[13];
    const float* go   = (const float*)d_in[14];
    const float* beo  = (const float*)d_in[15];

    float* ws = (float*)d_ws;
    float* xyzw  = ws + OFF_XYZW;
    float* pw1aT = ws + OFF_PW1AT;
    float* pw1bT = ws + OFF_PW1BT;
    float* pwvaT = ws + OFF_PWVAT;
    float* pwoT  = ws + OFF_PWOT;
    float* relw  = ws + OFF_RELW;
    float* stats = ws + OFF_STATS;
    int*   idx   = (int*)(ws + OFF_IDX);
    int*   pip   = (int*)(ws + OFF_PIP);
    float* outv  = ws + OFF_OUTV;   // aliases pip (dead after k_refine)
    float4* sx4  = (float4*)(ws + OFF_SX4);
    int*   sid   = (int*)(ws + OFF_SID);
    int*   hist  = (int*)(ws + OFF_HIST);
    float4* bbmn = (float4*)(ws + OFF_BB);
    float4* bbmx = (float4*)(ws + OFF_BB + 512);
    int*   rank  = (int*)(ws + OFF_RANK);
    float* ph    = ws + OFF_PH;
    float* po    = ws + OFF_PO;
    int*   kc    = (int*)(ws + OFF_KC);
    float* F1    = ws + OFF_F1;
    float* F2    = ws + OFF_F2;
    float* FV    = ws + OFF_FV;
    float* opre  = ws + OFF_OPRE;   // aliases F1 (dead after k_attn)

    k_zero<<<1, 256, 0, stream>>>(hist);
    k_prep<<<129, 256, 0, stream>>>(xyz, W1, Wv, Wo, xyzw, hist,
                                    pw1aT, pw1bT, pwvaT, pwoT, relw, stats);
    k_scan<<<4, 256, 0, stream>>>(hist);
    k_scatter<<<128, 256, 0, stream>>>((const float4*)xyzw, hist, sx4, sid, rank);
    k_bbox<<<128, 256, 0, stream>>>((const float4*)sx4, bbmn, bbmx);
    k_F<<<512, 256, 0, stream>>>(feats, b1, bv, pw1aT, pw1bT, pwvaT, rank, F1, F2, FV);
    k_knn<<<8192, 256, 0, stream>>>((const float4*)sx4, bbmn, bbmx, pip, kc);
    k_refine<<<128, 256, 0, stream>>>((const float4*)sx4, sid, pip, kc, idx);
    k_hv<<<2048, 256, 0, stream>>>((const float4*)sx4, idx, F1, F2, FV, relw, ph);
    k_red1<<<32, 256, 0, stream>>>(ph, stats);
    k_attn<<<8192, 256, 0, stream>>>((const float4*)sx4, idx, F1, F2, FV, relw, stats,
                                     g1, be1, W2, b2, gv, bev, outv);
    k_o<<<512, 256, 0, stream>>>(outv, pwoT, bo, sid, opre, po);
    k_red2<<<8, 256, 0, stream>>>(po, stats);
    k_final<<<512, 256, 0, stream>>>(opre, stats, go, beo, feats, (float*)d_out);
}

// Round 11
// 402.485 us; speedup vs baseline: 1.1092x; 1.1092x over previous
//
#include <hip/hip_runtime.h>
#include <math.h>

// Problem constants
#define BB 4
#define NN 8192
#define CC 64
#define KK 16
#define HH 64
#define NPTS (BB*NN)   // 32768
#define EPSBN 1e-5f
#define CAP 64         // candidate buffer per query (fp64 refine picks 16)
#define NCELL 4096     // 16^3 Morton cells
#define CHN 128        // chunks per batch
#define CHSZ 64        // points per chunk

// ---------------- ws layout (float offsets) ----------------
#define OFF_XYZW  0
#define OFF_PW1AT 131072
#define OFF_PW1BT 135168
#define OFF_PWVAT 139264
#define OFF_PWOT  143360
#define OFF_RELW  147456
#define OFF_STATS 147840
#define OFF_IDX   148224      // idx: 32768*16 ints (SORTED-space neighbor ids)
#define OFF_PIP   672512      // pip: 32768*CAP ints (dead after k_refine)
#define OFF_OUTV  672512      // OUTV aliases PIP: [32768][64] sorted attention output
#define OFF_SX4   2769664     // sorted xyzw [4][8192] float4
#define OFF_SID   2900736     // sorted->orig ids [4][8192] int
#define OFF_HIST  2933504     // [4][4096] int
#define OFF_RANK  2950912     // orig->sorted rank [4][8192] int
#define OFF_PH    2983680     // k_hv block partials [2048][256]
#define OFF_PO    3507968     // k_o block partials [512][128]
#define OFF_KC    3573504     // per-query candidate count [32768] int
#define OFF_BB    3606272     // bbmin[512] f4 (2048) + bbmax[512] f4 (2048)
#define OFF_F1    4866816     // SORTED layout (dead after k_attn)
#define OFF_OPRE  4866816     // OPRE aliases F1: [32768][64] original layout
#define OFF_F2    6963968     // SORTED layout
#define OFF_FV    9061120     // SORTED layout

__device__ __forceinline__ int morton_cell(float x, float y, float z) {
    int cx = (int)floorf((x + 4.f) * 2.f);
    int cy = (int)floorf((y + 4.f) * 2.f);
    int cz = (int)floorf((z + 4.f) * 2.f);
    cx = cx < 0 ? 0 : (cx > 15 ? 15 : cx);
    cy = cy < 0 ? 0 : (cy > 15 ? 15 : cy);
    cz = cz < 0 ? 0 : (cz > 15 ? 15 : cz);
    int ex = (cx & 1) | ((cx & 2) << 2) | ((cx & 4) << 4) | ((cx & 8) << 6);
    int ey = (cy & 1) | ((cy & 2) << 2) | ((cy & 4) << 4) | ((cy & 8) << 6);
    int ez = (cz & 1) | ((cz & 2) << 2) | ((cz & 4) << 4) | ((cz & 8) << 6);
    return ex | (ey << 1) | (ez << 2);
}

__device__ __forceinline__ float distf(float4 me, float jx, float jy, float jz, float jw) {
    float dot = fmaf(me.z, jz, fmaf(me.y, jy, me.x * jx));
    return fmaf(-2.f, dot, me.w) + jw;
}

__device__ __forceinline__ float mind2(float4 me, float4 bmin, float4 bmax) {
    float dx = fmaxf(fmaxf(bmin.x - me.x, me.x - bmax.x), 0.f);
    float dy = fmaxf(fmaxf(bmin.y - me.y, me.y - bmax.y), 0.f);
    float dz = fmaxf(fmaxf(bmin.z - me.z, me.z - bmax.z), 0.f);
    return fmaf(dx, dx, fmaf(dy, dy, dz * dz));
}

__device__ __forceinline__ int mbcnt64(unsigned long long m) {
    return __builtin_amdgcn_mbcnt_hi((unsigned int)(m >> 32),
           __builtin_amdgcn_mbcnt_lo((unsigned int)m, 0));
}

__global__ __launch_bounds__(256) void k_zero(int* __restrict__ hist) {
    int t = threadIdx.x;
    for (int i = t; i < BB * NCELL; i += 256) hist[i] = 0;
}

__global__ __launch_bounds__(256) void k_prep(
    const float* __restrict__ xyz, const float* __restrict__ W1,
    const float* __restrict__ Wv, const float* __restrict__ Wo,
    float* __restrict__ xyzw, int* __restrict__ hist,
    float* __restrict__ pw1aT, float* __restrict__ pw1bT,
    float* __restrict__ pwvaT, float* __restrict__ pwoT, float* __restrict__ relw,
    float* __restrict__ stats)
{
    int t = threadIdx.x;
    int bid = blockIdx.x;
    if (bid < 128) {
        int pt = bid * 256 + t;
        int b = pt >> 13, n = pt & 8191;
        const float* xb = xyz + (size_t)b * 3 * NN;
        float x = xb[n], y = xb[NN + n], z = xb[2 * NN + n];
        float sq = __fadd_rn(__fadd_rn(__fmul_rn(x, x), __fmul_rn(y, y)), __fmul_rn(z, z));
        ((float4*)xyzw)[pt] = make_float4(x, y, z, sq);
        atomicAdd(&hist[b * NCELL + morton_cell(x, y, z)], 1);
    } else {
        for (int e = t; e < 4096; e += 256) {
            int c = e >> 6, o = e & 63;
            pw1aT[e] = W1[o * 131 + c];
            pw1bT[e] = W1[o * 131 + 64 + c];
            pwvaT[e] = Wv[o * 67 + c];
            pwoT[e]  = Wo[o * 64 + c];
        }
        for (int e = t; e < 384; e += 256) {
            int d = e >> 6, o = e & 63;
            relw[e] = (d < 3) ? W1[o * 131 + 128 + d] : Wv[o * 67 + 64 + (d - 3)];
            stats[e] = 0.0f;
        }
    }
}

// Exclusive scan of per-batch 4096-bin histogram (in place), one block per batch.
__global__ __launch_bounds__(256) void k_scan(int* __restrict__ hist) {
    __shared__ int part[256];
    int b = blockIdx.x, t = threadIdx.x;
    int* h = hist + b * NCELL;
    int loc[16]; int s = 0;
#pragma unroll
    for (int i = 0; i < 16; i++) { loc[i] = h[t * 16 + i]; s += loc[i]; }
    part[t] = s;
    __syncthreads();
    for (int off = 1; off < 256; off <<= 1) {
        int v = (t >= off) ? part[t - off] : 0;
        __syncthreads();
        part[t] += v;
        __syncthreads();
    }
    int run = (t > 0) ? part[t - 1] : 0;
#pragma unroll
    for (int i = 0; i < 16; i++) { int c = loc[i]; h[t * 16 + i] = run; run += c; }
}

__global__ __launch_bounds__(256) void k_scatter(
    const float4* __restrict__ xyzw, int* __restrict__ off,
    float4* __restrict__ sx4, int* __restrict__ sid, int* __restrict__ rank)
{
    int pt = blockIdx.x * 256 + threadIdx.x;
    int b = pt >> 13, n = pt & 8191;
    float4 p = xyzw[pt];
    int cell = morton_cell(p.x, p.y, p.z);
    int dst = atomicAdd(&off[b * NCELL + cell], 1);
    sx4[(b << 13) + dst] = p;
    sid[(b << 13) + dst] = n;
    rank[pt] = dst;
}

// Per-chunk bbox over 64 sorted points. One wave per chunk; 512 chunks total.
__global__ __launch_bounds__(256) void k_bbox(
    const float4* __restrict__ sx4, float4* __restrict__ bbmin, float4* __restrict__ bbmax)
{
    int t = threadIdx.x, lane = t & 63, wl = t >> 6;
    int ch = blockIdx.x * 4 + wl;             // 0..511
    float4 p = sx4[ch * CHSZ + lane];
    float mnx = p.x, mny = p.y, mnz = p.z, mxx = p.x, mxy = p.y, mxz = p.z;
#pragma unroll
    for (int o = 32; o >= 1; o >>= 1) {
        mnx = fminf(mnx, __shfl_xor(mnx, o, 64)); mxx = fmaxf(mxx, __shfl_xor(mxx, o, 64));
        mny = fminf(mny, __shfl_xor(mny, o, 64)); mxy = fmaxf(mxy, __shfl_xor(mxy, o, 64));
        mnz = fminf(mnz, __shfl_xor(mnz, o, 64)); mxz = fmaxf(mxz, __shfl_xor(mxz, o, 64));
    }
    if (lane == 0) {
        bbmin[ch] = make_float4(mnx, mny, mnz, 0.f);
        bbmax[ch] = make_float4(mxx, mxy, mxz, 0.f);
    }
}

// KNN candidate collection. Window sort -> tau = 16th-best (+margin; refine only
// needs a superset of fp64-top-16 and the window seeds >=16 entries). Chunk mask
// over 128 tight 64-pt chunks (2 ballots); each surviving chunk = one 64-lane
// step with ballot+mbcnt prefix-append. Rare overflow -> verified sorted-insert.
__global__ __launch_bounds__(256) void k_knn(
    const float4* __restrict__ sx4,
    const float4* __restrict__ bbmin, const float4* __restrict__ bbmax,
    int* __restrict__ pip, int* __restrict__ kc)
{
    int t = threadIdx.x, lane = t & 63, wl = t >> 6;
    int gq = blockIdx.x * 4 + wl;
    int b = __builtin_amdgcn_readfirstlane(gq >> 13);
    int qs = gq & 8191;
    const float4* sb = sx4 + ((size_t)b << 13);
    float4 me = sb[qs];                       // wave-uniform
    const float INF = 3.402823466e38f;

    // phase 1: bitonic-sort the 64-point positional window
    int ws0 = qs - 32; ws0 = ws0 < 0 ? 0 : (ws0 > (NN - 64) ? (NN - 64) : ws0);
    float4 cp = sb[ws0 + lane];
    int cid = ws0 + lane;                     // sorted-space id
    float d = distf(me, cp.x, cp.y, cp.z, cp.w);
#pragma unroll
    for (int k2 = 2; k2 <= 64; k2 <<= 1) {
#pragma unroll
        for (int j2 = k2 >> 1; j2 >= 1; j2 >>= 1) {
            float od = __shfl_xor(d, j2, 64);
            int   oi = __shfl_xor(cid, j2, 64);
            bool up = ((lane & k2) == 0);
            bool lower = ((lane & j2) == 0);
            bool wantMin = (lower == up);
            bool to = wantMin ? (od < d) : (od > d);
            d = to ? od : d; cid = to ? oi : cid;
        }
    }
    // tau from the 16th smallest (lane 15): superset of fp64 top-16 guaranteed
    // (window 16th >= global 16th; fp32 error ~2e-6 << margin).
    float tau = __int_as_float(__builtin_amdgcn_readlane(__float_as_int(d), 15));
    float tauA = tau * 1.0001f + 1e-5f;
    int* row = pip + (size_t)gq * CAP;

    // chunk masks (evaluated once; reused by fallback with larger tau)
    float md0 = mind2(me, bbmin[b * CHN + lane], bbmax[b * CHN + lane]);
    float md1 = mind2(me, bbmin[b * CHN + 64 + lane], bbmax[b * CHN + 64 + lane]);

    {
        // seed with window entries <= tauA (sorted lanes -> contiguous mask)
        bool hit = (d <= tauA);
        unsigned long long hm = __ballot(hit);
        if (hit) row[mbcnt64(hm)] = cid;
        int cnt = __popcll(hm);

        unsigned long long bm0 = __ballot(md0 <= tauA);
        unsigned long long bm1 = __ballot(md1 <= tauA);

        while (bm0 | bm1) {
            int c;
            if (bm0) { c = __builtin_ctzll(bm0); bm0 &= bm0 - 1; }
            else     { c = 64 + __builtin_ctzll(bm1); bm1 &= bm1 - 1; }
            int pos = c * CHSZ + lane;
            float4 p = sb[pos];
            float dd = distf(me, p.x, p.y, p.z, p.w);
            bool inwin = (pos >= ws0) && (pos < ws0 + 64);
            bool hit2 = (dd <= tauA) && !inwin;
            unsigned long long m2 = __ballot(hit2);
            if (hit2) {
                int slot = cnt + mbcnt64(m2);
                if (slot < CAP) row[slot] = pos;
            }
            cnt += __popcll(m2);
        }

        if (cnt <= CAP) {
            if (lane == 0) kc[gq] = cnt;
            return;
        }
    }

    // ---- rare fallback: verified sorted-insert top-32 (window-seeded) ----
    {
        bool lt32 = (lane < 32);
        float val = lt32 ? d : INF;
        int vid = cid;
        float tau2 = __int_as_float(__builtin_amdgcn_readlane(__float_as_int(val), 31));
        float t2A = tau2 * 1.0001f + 1e-5f;
        unsigned long long fb0 = __ballot(md0 <= t2A);
        unsigned long long fb1 = __ballot(md1 <= t2A);
        while (fb0 | fb1) {
            int c;
            if (fb0) { c = __builtin_ctzll(fb0); fb0 &= fb0 - 1; }
            else     { c = 64 + __builtin_ctzll(fb1); fb1 &= fb1 - 1; }
            int pos = c * CHSZ + lane;
            float4 p = sb[pos];
            float dd = distf(me, p.x, p.y, p.z, p.w);
            bool inwin = (pos >= ws0) && (pos < ws0 + 64);
            dd = inwin ? INF : dd;
            unsigned long long m = __ballot(dd < tau2);
            while (m) {
                int hl = __builtin_ctzll(m); m &= m - 1;
                float dn = __int_as_float(
                    __builtin_amdgcn_readlane(__float_as_int(dd), hl));
                int jn = c * CHSZ + hl;
                unsigned long long bl = __ballot(val < dn);
                int pos2 = __popcll(bl);
                float sv = __shfl_up(val, 1, 64);
                int   sj = __shfl_up(vid, 1, 64);
                float nv = (lane > pos2) ? sv : val; nv = (lane == pos2) ? dn : nv;
                int   nj = (lane > pos2) ? sj : vid; nj = (lane == pos2) ? jn : nj;
                val = lt32 ? nv : val;
                vid = lt32 ? nj : vid;
                tau2 = __int_as_float(__builtin_amdgcn_readlane(__float_as_int(val), 31));
            }
        }
        if (lt32) row[lane] = vid;
        if (lane == 0) kc[gq] = 32;
    }
}

// Exact refinement in SORTED space: fp64 distances for kc[gq] candidates,
// top-16 by (d, ORIGINAL index). Outputs sorted-space ids.
__global__ __launch_bounds__(256) void k_refine(
    const float4* __restrict__ sx4, const int* __restrict__ sid,
    const int* __restrict__ pip, const int* __restrict__ kc, int* __restrict__ idx)
{
    int gq = blockIdx.x * 256 + threadIdx.x;
    int b = gq >> 13;
    const float4* sb = sx4 + ((size_t)b << 13);
    const int* ib = sid + ((size_t)b << 13);
    float4 mef = sb[gq & 8191];
    double mx = (double)mef.x, my = (double)mef.y, mz = (double)mef.z;
    double msq = (mx * mx + my * my) + mz * mz;
    int cnt = kc[gq];
    double bd[16]; int bi[16]; int bo[16];
#pragma unroll
    for (int s = 0; s < 16; s++) { bd[s] = 1e300; bi[s] = 0; bo[s] = 0x7fffffff; }
    for (int c = 0; c < cnt; c++) {
        int j = pip[(size_t)gq * CAP + c];
        float4 cj = sb[j];
        int oj = ib[j];
        double jx = (double)cj.x, jy = (double)cj.y, jz = (double)cj.z;
        double dot = (mx * jx + my * jy) + mz * jz;
        double sqj = (jx * jx + jy * jy) + jz * jz;
        double dd = (-2.0 * dot + msq) + sqj;
        if (dd < bd[15] || (dd == bd[15] && oj < bo[15])) {
            double pd_ = dd; int pi_ = j; int po_ = oj;
#pragma unroll
            for (int s = 15; s >= 1; s--) {
                bool cc = (pd_ < bd[s - 1]) || (pd_ == bd[s - 1] && po_ < bo[s - 1]);
                double nd = cc ? bd[s - 1] : pd_;  int ni = cc ? bi[s - 1] : pi_;  int no = cc ? bo[s - 1] : po_;
                double npd = cc ? pd_ : bd[s - 1]; int npi = cc ? pi_ : bi[s - 1]; int npo = cc ? po_ : bo[s - 1];
                bd[s] = nd; bi[s] = ni; bo[s] = no; pd_ = npd; pi_ = npi; po_ = npo;
            }
            bd[0] = pd_; bi[0] = pi_; bo[0] = po_;
        }
    }
#pragma unroll
    for (int s = 0; s < 16; s++) idx[(size_t)gq * 16 + s] = bi[s];
}

// Per-point GEMVs, output scattered to SORTED layout via rank.
__global__ __launch_bounds__(256) void k_F(
    const float* __restrict__ feats, const float* __restrict__ b1, const float* __restrict__ bv,
    const float* __restrict__ pw1aT, const float* __restrict__ pw1bT, const float* __restrict__ pwvaT,
    const int* __restrict__ rank,
    float* __restrict__ F1, float* __restrict__ F2, float* __restrict__ FV)
{
    int t = threadIdx.x;
    int lane = t & 63;
    int wave = t >> 6;
    int pt0 = blockIdx.x * 64 + wave * 16;
    int b   = __builtin_amdgcn_readfirstlane(pt0 >> 13);
    int n0  = __builtin_amdgcn_readfirstlane(pt0 & 8191);
    const float* fb = feats + (size_t)b * CC * NN;
    float accA[16], accB[16], accV[16];
    float bb1 = b1[lane], bbv = bv[lane];
#pragma unroll
    for (int p = 0; p < 16; p++) { accA[p] = bb1; accB[p] = 0.f; accV[p] = bbv; }
    for (int c = 0; c < 64; c++) {
        float wA = pw1aT[c * 64 + lane];
        float wB = pw1bT[c * 64 + lane];
        float wV = pwvaT[c * 64 + lane];
        const float* fr = fb + (size_t)c * NN + n0;
#pragma unroll
        for (int p = 0; p < 16; p++) {
            float f = fr[p];
            accA[p] = fmaf(wA, f, accA[p]);
            accB[p] = fmaf(wB, f, accB[p]);
            accV[p] = fmaf(wV, f, accV[p]);
        }
    }
#pragma unroll
    for (int p = 0; p < 16; p++) {
        int dst = (b << 13) + rank[pt0 + p];     // wave-uniform scalar
        F1[(size_t)dst * 64 + lane] = accA[p];
        F2[(size_t)dst * 64 + lane] = accB[p];
        FV[(size_t)dst * 64 + lane] = accV[p];
    }
}

// BN stats pass. XCD-swizzled; block partials to PH (NO contended atomics).
__global__ __launch_bounds__(256) void k_hv(
    const float4* __restrict__ sx4, const int* __restrict__ idx,
    const float* __restrict__ F1, const float* __restrict__ F2, const float* __restrict__ FV,
    const float* __restrict__ relw, float* __restrict__ ph)
{
    __shared__ float red[4][4][64];
    int t = threadIdx.x;
    int lane = t & 63;
    int wl = t >> 6;
    int bx = blockIdx.x;                       // 2048 blocks
    int vb = (bx & 7) * 256 + (bx >> 3);       // XCD-aware swizzle
    float rw0 = relw[0 * 64 + lane], rw1 = relw[1 * 64 + lane], rw2 = relw[2 * 64 + lane];
    float rw3 = relw[3 * 64 + lane], rw4 = relw[4 * 64 + lane], rw5 = relw[5 * 64 + lane];
    float sh = 0.f, sh2 = 0.f, sv = 0.f, sv2 = 0.f;
    for (int i = 0; i < 4; i++) {
        int gq = __builtin_amdgcn_readfirstlane(vb * 16 + wl * 4 + i);  // contiguous
        int b = gq >> 13;
        const float4* sb = sx4 + ((size_t)b << 13);
        float4 me = sb[gq & 8191];
        float F1v = F1[(size_t)gq * 64 + lane];
        const int* ip = idx + (size_t)gq * 16;
#pragma unroll
        for (int kb = 0; kb < 2; kb++) {
            float4 cjA[8]; float f2A[8], fvA[8];
#pragma unroll
            for (int j = 0; j < 8; j++) {
                int gl = ip[kb * 8 + j];
                cjA[j] = sb[gl];
                size_t go = (size_t)((b << 13) + gl) * 64 + lane;
                f2A[j] = F2[go];
                fvA[j] = FV[go];
            }
#pragma unroll
            for (int j = 0; j < 8; j++) {
                float rx = cjA[j].x - me.x, ry = cjA[j].y - me.y, rz = cjA[j].z - me.z;
                float h = F1v + f2A[j];
                h = fmaf(rw0, rx, h); h = fmaf(rw1, ry, h); h = fmaf(rw2, rz, h);
                float v = fvA[j];
                v = fmaf(rw3, rx, v); v = fmaf(rw4, ry, v); v = fmaf(rw5, rz, v);
                sh += h; sh2 = fmaf(h, h, sh2);
                sv += v; sv2 = fmaf(v, v, sv2);
            }
        }
    }
    red[0][wl][lane] = sh; red[1][wl][lane] = sh2;
    red[2][wl][lane] = sv; red[3][wl][lane] = sv2;
    __syncthreads();
    float s = red[wl][0][lane] + red[wl][1][lane] + red[wl][2][lane] + red[wl][3][lane];
    ph[(size_t)bx * 256 + wl * 64 + lane] = s;     // plain store, no contention
}

// Reduce PH -> stats[0..255]. 32 blocks x 64 rows each; light atomics (32/addr).
__global__ __launch_bounds__(256) void k_red1(
    const float* __restrict__ ph, float* __restrict__ stats)
{
    int t = threadIdx.x, p = blockIdx.x;
    float acc = 0.f;
    for (int i = 0; i < 64; i++)
        acc += ph[(size_t)(p * 64 + i) * 256 + t];
    atomicAdd(&stats[t], acc);
}

// Attention in SORTED space, XCD-swizzled. Barrier-free, atomic-free, LDS-free.
__global__ __launch_bounds__(256) void k_attn(
    const float4* __restrict__ sx4,
    const int* __restrict__ idx,
    const float* __restrict__ F1, const float* __restrict__ F2, const float* __restrict__ FV,
    const float* __restrict__ relw, const float* __restrict__ stats,
    const float* __restrict__ g1, const float* __restrict__ be1,
    const float* __restrict__ W2, const float* __restrict__ b2,
    const float* __restrict__ gv, const float* __restrict__ bev,
    float* __restrict__ outv)
{
    int t = threadIdx.x;
    int lane = t & 63;
    int wl = t >> 6;
    int bx = blockIdx.x;                      // 8192 blocks
    int vb = (bx & 7) * 1024 + (bx >> 3);     // XCD-aware swizzle
    int gq = vb * 4 + wl;                     // sorted-global query
    const float invM = 1.f / 524288.f;
    float hm = stats[lane] * invM, hq = stats[64 + lane] * invM;
    float s1 = g1[lane] * rsqrtf(hq - hm * hm + EPSBN);
    float t1 = be1[lane] - s1 * hm;
    float vm = stats[128 + lane] * invM, vq = stats[192 + lane] * invM;
    float sv = gv[lane] * rsqrtf(vq - vm * vm + EPSBN);
    float tv = bev[lane] - sv * vm;
    float rw0 = relw[0 * 64 + lane], rw1 = relw[1 * 64 + lane], rw2 = relw[2 * 64 + lane];
    float rw3 = relw[3 * 64 + lane], rw4 = relw[4 * 64 + lane], rw5 = relw[5 * 64 + lane];
    float w2v = W2[lane];
    float b2v = b2[0];

    int b = __builtin_amdgcn_readfirstlane(gq >> 13);
    const float4* sb = sx4 + ((size_t)b << 13);
    float4 me = sb[gq & 8191];
    float F1v = F1[(size_t)gq * 64 + lane];
    const int* ip = idx + (size_t)gq * 16;
    float ek[16], vk[16];
#pragma unroll
    for (int kb = 0; kb < 2; kb++) {
        float4 cjA[8]; float f2A[8], fvA[8];
#pragma unroll
        for (int j = 0; j < 8; j++) {
            int gl = ip[kb * 8 + j];
            cjA[j] = sb[gl];
            size_t go = (size_t)((b << 13) + gl) * 64 + lane;
            f2A[j] = F2[go];
            fvA[j] = FV[go];
        }
#pragma unroll
        for (int j = 0; j < 8; j++) {
            int k = kb * 8 + j;
            float rx = cjA[j].x - me.x, ry = cjA[j].y - me.y, rz = cjA[j].z - me.z;
            float h = F1v + f2A[j];
            h = fmaf(rw0, rx, h); h = fmaf(rw1, ry, h); h = fmaf(rw2, rz, h);
            float a = fmaxf(fmaf(s1, h, t1), 0.f);
            float v = fvA[j];
            v = fmaf(rw3, rx, v); v = fmaf(rw4, ry, v); v = fmaf(rw5, rz, v);
            vk[k] = fmaxf(fmaf(sv, v, tv), 0.f);
            float lg = w2v * a;
#pragma unroll
            for (int off = 32; off >= 1; off >>= 1) lg += __shfl_xor(lg, off, 64);
            ek[k] = lg + b2v;
        }
    }
    float mx = ek[0];
#pragma unroll
    for (int k = 1; k < 16; k++) mx = fmaxf(mx, ek[k]);
    float ssum = 0.f;
#pragma unroll
    for (int k = 0; k < 16; k++) { float e = __expf(ek[k] - mx); ek[k] = e; ssum += e; }
    float acc = 0.f;
#pragma unroll
    for (int k = 0; k < 16; k++) acc = fmaf(ek[k], vk[k], acc);
    outv[(size_t)gq * 64 + lane] = acc / ssum;
}

// Wo matvec + o-stats: out rows (sorted) -> o_pre rows (ORIGINAL layout) + PO partials.
__global__ __launch_bounds__(256) void k_o(
    const float* __restrict__ outv, const float* __restrict__ pwoT,
    const float* __restrict__ bo, const int* __restrict__ sid,
    float* __restrict__ opre, float* __restrict__ po)
{
    __shared__ float red[2][4][64];
    int t = threadIdx.x;
    int lane = t & 63;
    int wl = t >> 6;
    int gq0 = blockIdx.x * 64 + wl * 16;       // 16 sorted points per wave
    int b = __builtin_amdgcn_readfirstlane(gq0 >> 13);
    float acc[16];
    float bov = bo[lane];
#pragma unroll
    for (int p = 0; p < 16; p++) acc[p] = bov;
    for (int c = 0; c < 64; c++) {
        float w = pwoT[c * 64 + lane];
        const float* orow = outv + (size_t)gq0 * 64 + c;
#pragma unroll
        for (int p = 0; p < 16; p++)
            acc[p] = fmaf(w, orow[p * 64], acc[p]);
    }
    float so = 0.f, so2 = 0.f;
#pragma unroll
    for (int p = 0; p < 16; p++) {
        int orig = (b << 13) + sid[gq0 + p];   // wave-uniform scalar
        opre[(size_t)orig * 64 + lane] = acc[p];
        so += acc[p]; so2 = fmaf(acc[p], acc[p], so2);
    }
    red[0][wl][lane] = so; red[1][wl][lane] = so2;
    __syncthreads();
    if (wl < 2) {
        float s = red[wl][0][lane] + red[wl][1][lane] + red[wl][2][lane] + red[wl][3][lane];
        po[(size_t)blockIdx.x * 128 + wl * 64 + lane] = s;
    }
}

// Reduce PO -> stats[256..383]. 8 blocks x 64 rows; light atomics.
__global__ __launch_bounds__(256) void k_red2(
    const float* __restrict__ po, float* __restrict__ stats)
{
    int t = threadIdx.x, p = blockIdx.x;
    if (t < 128) {
        float acc = 0.f;
        for (int i = 0; i < 64; i++)
            acc += po[(size_t)(p * 64 + i) * 128 + t];
        atomicAdd(&stats[256 + t], acc);
    }
}

// Final: BN(o)+relu + residual feats, transpose [B,N,C]->[B,C,N]
__global__ __launch_bounds__(256) void k_final(
    const float* __restrict__ opre, const float* __restrict__ stats,
    const float* __restrict__ go, const float* __restrict__ beo,
    const float* __restrict__ feats, float* __restrict__ out)
{
    __shared__ float tile[64][65];
    int t = threadIdx.x;
    int blk = blockIdx.x;
    int b = blk >> 7, n0 = (blk & 127) << 6;
#pragma unroll
    for (int i = 0; i < 16; i++) {
        int e = t + i * 256;
        int r = e >> 6, c = e & 63;
        tile[r][c] = opre[((size_t)((b << 13) + n0 + r)) * 64 + c];
    }
    __syncthreads();
    const float invM = 1.f / 32768.f;
    int lane = t & 63, wv = t >> 6;
#pragma unroll
    for (int i = 0; i < 16; i++) {
        int c = wv * 16 + i;
        float om = stats[256 + c] * invM, oq = stats[320 + c] * invM;
        float so = go[c] * rsqrtf(oq - om * om + EPSBN);
        float to = beo[c] - so * om;
        float val = fmaxf(fmaf(so, tile[lane][c], to), 0.f);
        size_t oix = ((size_t)b * 64 + c) * NN + n0 + lane;
        out[oix] = val + feats[oix];
    }
}

extern "C" void kernel_launch(void* const* d_in, const int* in_sizes, int n_in,
                              void* d_out, int out_size, void* d_ws, size_t ws_size,
                              hipStream_t stream)
{
    const float* xyz  = (const float*)d_in[0];
    const float* feats= (const float*)d_in[1];
    const float* W1   = (const float*)d_in[2];
    const float* b1   = (const float*)d_in[3];
    const float* g1   = (const float*)d_in[4];
    const float* be1  = (const float*)d_in[5];
    const float* W2   = (const float*)d_in[6];
    const float* b2   = (const float*)d_in[7];
    const float* Wv   = (const float*)d_in[8];
    const float* bv   = (const float*)d_in[9];
    const float* gv   = (const float*)d_in[10];
    const float* bev  = (const float*)d_in[11];
    const float* Wo   = (const float*)d_in[12];
    const float* bo   = (const float*)d_in[13];
    const float* go   = (const float*)d_in[14];
    const float* beo  = (const float*)d_in[15];

    float* ws = (float*)d_ws;
    float* xyzw  = ws + OFF_XYZW;
    float* pw1aT = ws + OFF_PW1AT;
    float* pw1bT = ws + OFF_PW1BT;
    float* pwvaT = ws + OFF_PWVAT;
    float* pwoT  = ws + OFF_PWOT;
    float* relw  = ws + OFF_RELW;
    float* stats = ws + OFF_STATS;
    int*   idx   = (int*)(ws + OFF_IDX);
    int*   pip   = (int*)(ws + OFF_PIP);
    float* outv  = ws + OFF_OUTV;   // aliases pip (dead after k_refine)
    float4* sx4  = (float4*)(ws + OFF_SX4);
    int*   sid   = (int*)(ws + OFF_SID);
    int*   hist  = (int*)(ws + OFF_HIST);
    float4* bbmn = (float4*)(ws + OFF_BB);
    float4* bbmx = (float4*)(ws + OFF_BB + 2048);
    int*   rank  = (int*)(ws + OFF_RANK);
    float* ph    = ws + OFF_PH;
    float* po    = ws + OFF_PO;
    int*   kc    = (int*)(ws + OFF_KC);
    float* F1    = ws + OFF_F1;
    float* F2    = ws + OFF_F2;
    float* FV    = ws + OFF_FV;
    float* opre  = ws + OFF_OPRE;   // aliases F1 (dead after k_attn)

    k_zero<<<1, 256, 0, stream>>>(hist);
    k_prep<<<129, 256, 0, stream>>>(xyz, W1, Wv, Wo, xyzw, hist,
                                    pw1aT, pw1bT, pwvaT, pwoT, relw, stats);
    k_scan<<<4, 256, 0, stream>>>(hist);
    k_scatter<<<128, 256, 0, stream>>>((const float4*)xyzw, hist, sx4, sid, rank);
    k_bbox<<<128, 256, 0, stream>>>((const float4*)sx4, bbmn, bbmx);
    k_F<<<512, 256, 0, stream>>>(feats, b1, bv, pw1aT, pw1bT, pwvaT, rank, F1, F2, FV);
    k_knn<<<8192, 256, 0, stream>>>((const float4*)sx4, bbmn, bbmx, pip, kc);
    k_refine<<<128, 256, 0, stream>>>((const float4*)sx4, sid, pip, kc, idx);
    k_hv<<<2048, 256, 0, stream>>>((const float4*)sx4, idx, F1, F2, FV, relw, ph);
    k_red1<<<32, 256, 0, stream>>>(ph, stats);
    k_attn<<<8192, 256, 0, stream>>>((const float4*)sx4, idx, F1, F2, FV, relw, stats,
                                     g1, be1, W2, b2, gv, bev, outv);
    k_o<<<512, 256, 0, stream>>>(outv, pwoT, bo, sid, opre, po);
    k_red2<<<8, 256, 0, stream>>>(po, stats);
    k_final<<<512, 256, 0, stream>>>(opre, stats, go, beo, feats, (float*)d_out);
}

// Round 12
// 339.425 us; speedup vs baseline: 1.3152x; 1.1858x over previous
//
#include <hip/hip_runtime.h>
#include <math.h>

// Problem constants
#define BB 4
#define NN 8192
#define CC 64
#define KK 16
#define HH 64
#define NPTS (BB*NN)   // 32768
#define EPSBN 1e-5f
#define CAP 64         // candidate buffer per query (fp64 refine picks 16)
#define NCELL 4096     // 16^3 Morton cells
#define CHN 128        // chunks per batch
#define CHSZ 64        // points per chunk

// ---------------- ws layout (float offsets) ----------------
#define OFF_XYZW  0
#define OFF_PW1AT 131072
#define OFF_PW1BT 135168
#define OFF_PWVAT 139264
#define OFF_PWOT  143360
#define OFF_RELW  147456
#define OFF_STATS 147840
#define OFF_IDX   148224      // idx: 32768*16 ints (SORTED-space neighbor ids)
#define OFF_PIP   672512      // pip: 32768*CAP ints (dead after k_refine)
#define OFF_OUTV  672512      // OUTV aliases PIP: [32768][64] sorted attention output
#define OFF_SX4   2769664     // sorted xyzw [4][8192] float4
#define OFF_SID   2900736     // sorted->orig ids [4][8192] int
#define OFF_HIST  2933504     // [4][4096] int
#define OFF_RANK  2950912     // orig->sorted rank [4][8192] int
#define OFF_PH    2983680     // k_hv block partials [2048][256]
#define OFF_PO    3507968     // k_o block partials [512][128]
#define OFF_KC    3573504     // per-query candidate count [32768] int
#define OFF_BB    3606272     // bbmin[512] f4 (2048) + bbmax[512] f4 (2048)
#define OFF_F1    4866816     // SORTED layout (dead after k_attn)
#define OFF_OPRE  4866816     // OPRE aliases F1: [32768][64] original layout
#define OFF_F2    6963968     // SORTED layout
#define OFF_FV    9061120     // SORTED layout

__device__ __forceinline__ int morton_cell(float x, float y, float z) {
    int cx = (int)floorf((x + 4.f) * 2.f);
    int cy = (int)floorf((y + 4.f) * 2.f);
    int cz = (int)floorf((z + 4.f) * 2.f);
    cx = cx < 0 ? 0 : (cx > 15 ? 15 : cx);
    cy = cy < 0 ? 0 : (cy > 15 ? 15 : cy);
    cz = cz < 0 ? 0 : (cz > 15 ? 15 : cz);
    int ex = (cx & 1) | ((cx & 2) << 2) | ((cx & 4) << 4) | ((cx & 8) << 6);
    int ey = (cy & 1) | ((cy & 2) << 2) | ((cy & 4) << 4) | ((cy & 8) << 6);
    int ez = (cz & 1) | ((cz & 2) << 2) | ((cz & 4) << 4) | ((cz & 8) << 6);
    return ex | (ey << 1) | (ez << 2);
}

__device__ __forceinline__ float distf(float4 me, float jx, float jy, float jz, float jw) {
    float dot = fmaf(me.z, jz, fmaf(me.y, jy, me.x * jx));
    return fmaf(-2.f, dot, me.w) + jw;
}

__device__ __forceinline__ float mind2(float4 me, float4 bmin, float4 bmax) {
    float dx = fmaxf(fmaxf(bmin.x - me.x, me.x - bmax.x), 0.f);
    float dy = fmaxf(fmaxf(bmin.y - me.y, me.y - bmax.y), 0.f);
    float dz = fmaxf(fmaxf(bmin.z - me.z, me.z - bmax.z), 0.f);
    return fmaf(dx, dx, fmaf(dy, dy, dz * dz));
}

__device__ __forceinline__ int mbcnt64(unsigned long long m) {
    return __builtin_amdgcn_mbcnt_hi((unsigned int)(m >> 32),
           __builtin_amdgcn_mbcnt_lo((unsigned int)m, 0));
}

__global__ __launch_bounds__(256) void k_zero(int* __restrict__ hist) {
    int t = threadIdx.x;
    for (int i = t; i < BB * NCELL; i += 256) hist[i] = 0;
}

__global__ __launch_bounds__(256) void k_prep(
    const float* __restrict__ xyz, const float* __restrict__ W1,
    const float* __restrict__ Wv, const float* __restrict__ Wo,
    float* __restrict__ xyzw, int* __restrict__ hist,
    float* __restrict__ pw1aT, float* __restrict__ pw1bT,
    float* __restrict__ pwvaT, float* __restrict__ pwoT, float* __restrict__ relw,
    float* __restrict__ stats)
{
    int t = threadIdx.x;
    int bid = blockIdx.x;
    if (bid < 128) {
        int pt = bid * 256 + t;
        int b = pt >> 13, n = pt & 8191;
        const float* xb = xyz + (size_t)b * 3 * NN;
        float x = xb[n], y = xb[NN + n], z = xb[2 * NN + n];
        float sq = __fadd_rn(__fadd_rn(__fmul_rn(x, x), __fmul_rn(y, y)), __fmul_rn(z, z));
        ((float4*)xyzw)[pt] = make_float4(x, y, z, sq);
        atomicAdd(&hist[b * NCELL + morton_cell(x, y, z)], 1);
    } else {
        for (int e = t; e < 4096; e += 256) {
            int c = e >> 6, o = e & 63;
            pw1aT[e] = W1[o * 131 + c];
            pw1bT[e] = W1[o * 131 + 64 + c];
            pwvaT[e] = Wv[o * 67 + c];
            pwoT[e]  = Wo[o * 64 + c];
        }
        for (int e = t; e < 384; e += 256) {
            int d = e >> 6, o = e & 63;
            relw[e] = (d < 3) ? W1[o * 131 + 128 + d] : Wv[o * 67 + 64 + (d - 3)];
            stats[e] = 0.0f;
        }
    }
}

// Exclusive scan of per-batch 4096-bin histogram (in place), one block per batch.
__global__ __launch_bounds__(256) void k_scan(int* __restrict__ hist) {
    __shared__ int part[256];
    int b = blockIdx.x, t = threadIdx.x;
    int* h = hist + b * NCELL;
    int loc[16]; int s = 0;
#pragma unroll
    for (int i = 0; i < 16; i++) { loc[i] = h[t * 16 + i]; s += loc[i]; }
    part[t] = s;
    __syncthreads();
    for (int off = 1; off < 256; off <<= 1) {
        int v = (t >= off) ? part[t - off] : 0;
        __syncthreads();
        part[t] += v;
        __syncthreads();
    }
    int run = (t > 0) ? part[t - 1] : 0;
#pragma unroll
    for (int i = 0; i < 16; i++) { int c = loc[i]; h[t * 16 + i] = run; run += c; }
}

__global__ __launch_bounds__(256) void k_scatter(
    const float4* __restrict__ xyzw, int* __restrict__ off,
    float4* __restrict__ sx4, int* __restrict__ sid, int* __restrict__ rank)
{
    int pt = blockIdx.x * 256 + threadIdx.x;
    int b = pt >> 13, n = pt & 8191;
    float4 p = xyzw[pt];
    int cell = morton_cell(p.x, p.y, p.z);
    int dst = atomicAdd(&off[b * NCELL + cell], 1);
    sx4[(b << 13) + dst] = p;
    sid[(b << 13) + dst] = n;
    rank[pt] = dst;
}

// Per-chunk bbox over 64 sorted points. One wave per chunk; 512 chunks total.
__global__ __launch_bounds__(256) void k_bbox(
    const float4* __restrict__ sx4, float4* __restrict__ bbmin, float4* __restrict__ bbmax)
{
    int t = threadIdx.x, lane = t & 63, wl = t >> 6;
    int ch = blockIdx.x * 4 + wl;             // 0..511
    float4 p = sx4[ch * CHSZ + lane];
    float mnx = p.x, mny = p.y, mnz = p.z, mxx = p.x, mxy = p.y, mxz = p.z;
#pragma unroll
    for (int o = 32; o >= 1; o >>= 1) {
        mnx = fminf(mnx, __shfl_xor(mnx, o, 64)); mxx = fmaxf(mxx, __shfl_xor(mxx, o, 64));
        mny = fminf(mny, __shfl_xor(mny, o, 64)); mxy = fmaxf(mxy, __shfl_xor(mxy, o, 64));
        mnz = fminf(mnz, __shfl_xor(mnz, o, 64)); mxz = fmaxf(mxz, __shfl_xor(mxz, o, 64));
    }
    if (lane == 0) {
        bbmin[ch] = make_float4(mnx, mny, mnz, 0.f);
        bbmax[ch] = make_float4(mxx, mxy, mxz, 0.f);
    }
}

// KNN candidate collection. Window sort -> tau = 16th-best (+margin). Chunk mask
// over 128 tight 64-pt chunks; each surviving chunk = one 64-lane step with
// ballot+mbcnt prefix-append. Rare overflow -> verified sorted-insert.
__global__ __launch_bounds__(256) void k_knn(
    const float4* __restrict__ sx4,
    const float4* __restrict__ bbmin, const float4* __restrict__ bbmax,
    int* __restrict__ pip, int* __restrict__ kc)
{
    int t = threadIdx.x, lane = t & 63, wl = t >> 6;
    int gq = blockIdx.x * 4 + wl;
    int b = __builtin_amdgcn_readfirstlane(gq >> 13);
    int qs = gq & 8191;
    const float4* sb = sx4 + ((size_t)b << 13);
    float4 me = sb[qs];                       // wave-uniform
    const float INF = 3.402823466e38f;

    // phase 1: bitonic-sort the 64-point positional window
    int ws0 = qs - 32; ws0 = ws0 < 0 ? 0 : (ws0 > (NN - 64) ? (NN - 64) : ws0);
    float4 cp = sb[ws0 + lane];
    int cid = ws0 + lane;                     // sorted-space id
    float d = distf(me, cp.x, cp.y, cp.z, cp.w);
#pragma unroll
    for (int k2 = 2; k2 <= 64; k2 <<= 1) {
#pragma unroll
        for (int j2 = k2 >> 1; j2 >= 1; j2 >>= 1) {
            float od = __shfl_xor(d, j2, 64);
            int   oi = __shfl_xor(cid, j2, 64);
            bool up = ((lane & k2) == 0);
            bool lower = ((lane & j2) == 0);
            bool wantMin = (lower == up);
            bool to = wantMin ? (od < d) : (od > d);
            d = to ? od : d; cid = to ? oi : cid;
        }
    }
    // tau from the 16th smallest (lane 15): superset of fp64 top-16 guaranteed.
    float tau = __int_as_float(__builtin_amdgcn_readlane(__float_as_int(d), 15));
    float tauA = tau * 1.0001f + 1e-5f;
    int* row = pip + (size_t)gq * CAP;

    // chunk masks (evaluated once; reused by fallback with larger tau)
    float md0 = mind2(me, bbmin[b * CHN + lane], bbmax[b * CHN + lane]);
    float md1 = mind2(me, bbmin[b * CHN + 64 + lane], bbmax[b * CHN + 64 + lane]);

    {
        bool hit = (d <= tauA);
        unsigned long long hm = __ballot(hit);
        if (hit) row[mbcnt64(hm)] = cid;
        int cnt = __popcll(hm);

        unsigned long long bm0 = __ballot(md0 <= tauA);
        unsigned long long bm1 = __ballot(md1 <= tauA);

        while (bm0 | bm1) {
            int c;
            if (bm0) { c = __builtin_ctzll(bm0); bm0 &= bm0 - 1; }
            else     { c = 64 + __builtin_ctzll(bm1); bm1 &= bm1 - 1; }
            int pos = c * CHSZ + lane;
            float4 p = sb[pos];
            float dd = distf(me, p.x, p.y, p.z, p.w);
            bool inwin = (pos >= ws0) && (pos < ws0 + 64);
            bool hit2 = (dd <= tauA) && !inwin;
            unsigned long long m2 = __ballot(hit2);
            if (hit2) {
                int slot = cnt + mbcnt64(m2);
                if (slot < CAP) row[slot] = pos;
            }
            cnt += __popcll(m2);
        }

        if (cnt <= CAP) {
            if (lane == 0) kc[gq] = cnt;
            return;
        }
    }

    // ---- rare fallback: verified sorted-insert top-32 (window-seeded) ----
    {
        bool lt32 = (lane < 32);
        float val = lt32 ? d : INF;
        int vid = cid;
        float tau2 = __int_as_float(__builtin_amdgcn_readlane(__float_as_int(val), 31));
        float t2A = tau2 * 1.0001f + 1e-5f;
        unsigned long long fb0 = __ballot(md0 <= t2A);
        unsigned long long fb1 = __ballot(md1 <= t2A);
        while (fb0 | fb1) {
            int c;
            if (fb0) { c = __builtin_ctzll(fb0); fb0 &= fb0 - 1; }
            else     { c = 64 + __builtin_ctzll(fb1); fb1 &= fb1 - 1; }
            int pos = c * CHSZ + lane;
            float4 p = sb[pos];
            float dd = distf(me, p.x, p.y, p.z, p.w);
            bool inwin = (pos >= ws0) && (pos < ws0 + 64);
            dd = inwin ? INF : dd;
            unsigned long long m = __ballot(dd < tau2);
            while (m) {
                int hl = __builtin_ctzll(m); m &= m - 1;
                float dn = __int_as_float(
                    __builtin_amdgcn_readlane(__float_as_int(dd), hl));
                int jn = c * CHSZ + hl;
                unsigned long long bl = __ballot(val < dn);
                int pos2 = __popcll(bl);
                float sv = __shfl_up(val, 1, 64);
                int   sj = __shfl_up(vid, 1, 64);
                float nv = (lane > pos2) ? sv : val; nv = (lane == pos2) ? dn : nv;
                int   nj = (lane > pos2) ? sj : vid; nj = (lane == pos2) ? jn : nj;
                val = lt32 ? nv : val;
                vid = lt32 ? nj : vid;
                tau2 = __int_as_float(__builtin_amdgcn_readlane(__float_as_int(val), 31));
            }
        }
        if (lt32) row[lane] = vid;
        if (lane == 0) kc[gq] = 32;
    }
}

// Exact refinement, wave-parallel: ONE QUERY PER WAVE. Lane c holds candidate c
// (fp64 distance, exact), then a 21-stage wave bitonic sort on (d, orig_idx)
// keys -- strictly distinct (invalid lanes get unique sentinel ids) -- gives
// the full sorted order; lanes 0..15 write idx. Identical selection semantics
// to the serial insert (same (d,oj) total order).
__global__ __launch_bounds__(256) void k_refine(
    const float4* __restrict__ sx4, const int* __restrict__ sid,
    const int* __restrict__ pip, const int* __restrict__ kc, int* __restrict__ idx)
{
    int t = threadIdx.x, lane = t & 63, wl = t >> 6;
    int gq = blockIdx.x * 4 + wl;             // one query per wave
    int b = __builtin_amdgcn_readfirstlane(gq >> 13);
    const float4* sb = sx4 + ((size_t)b << 13);
    const int* ib = sid + ((size_t)b << 13);
    float4 mef = sb[gq & 8191];               // wave-uniform
    double mx = (double)mef.x, my = (double)mef.y, mz = (double)mef.z;
    double msq = (mx * mx + my * my) + mz * mz;
    int cnt = kc[gq];                          // wave-uniform

    int j = 0, oj = 0x40000000 + lane;         // sentinel: unique, > any valid oj
    double dd = 1e300;
    if (lane < cnt) {
        j = pip[(size_t)gq * CAP + lane];      // coalesced
        float4 cj = sb[j];
        oj = ib[j];
        double jx = (double)cj.x, jy = (double)cj.y, jz = (double)cj.z;
        double dot = (mx * jx + my * jy) + mz * jz;
        double sqj = (jx * jx + jy * jy) + jz * jz;
        dd = (-2.0 * dot + msq) + sqj;
    }
    // bitonic sort 64 by (dd, oj) ascending; keys strictly distinct
#pragma unroll
    for (int k2 = 2; k2 <= 64; k2 <<= 1) {
#pragma unroll
        for (int j2 = k2 >> 1; j2 >= 1; j2 >>= 1) {
            double od = __shfl_xor(dd, j2, 64);
            int   ooj = __shfl_xor(oj, j2, 64);
            int   oid = __shfl_xor(j, j2, 64);
            bool up = ((lane & k2) == 0);
            bool lower = ((lane & j2) == 0);
            bool wantMin = (lower == up);
            bool oless = (od < dd) || (od == dd && ooj < oj);
            bool take = wantMin ? oless : !oless;
            dd = take ? od : dd; oj = take ? ooj : oj; j = take ? oid : j;
        }
    }
    if (lane < 16) idx[(size_t)gq * 16 + lane] = j;
}

// Per-point GEMVs, output scattered to SORTED layout via rank.
__global__ __launch_bounds__(256) void k_F(
    const float* __restrict__ feats, const float* __restrict__ b1, const float* __restrict__ bv,
    const float* __restrict__ pw1aT, const float* __restrict__ pw1bT, const float* __restrict__ pwvaT,
    const int* __restrict__ rank,
    float* __restrict__ F1, float* __restrict__ F2, float* __restrict__ FV)
{
    int t = threadIdx.x;
    int lane = t & 63;
    int wave = t >> 6;
    int pt0 = blockIdx.x * 64 + wave * 16;
    int b   = __builtin_amdgcn_readfirstlane(pt0 >> 13);
    int n0  = __builtin_amdgcn_readfirstlane(pt0 & 8191);
    const float* fb = feats + (size_t)b * CC * NN;
    float accA[16], accB[16], accV[16];
    float bb1 = b1[lane], bbv = bv[lane];
#pragma unroll
    for (int p = 0; p < 16; p++) { accA[p] = bb1; accB[p] = 0.f; accV[p] = bbv; }
    for (int c = 0; c < 64; c++) {
        float wA = pw1aT[c * 64 + lane];
        float wB = pw1bT[c * 64 + lane];
        float wV = pwvaT[c * 64 + lane];
        const float* fr = fb + (size_t)c * NN + n0;
#pragma unroll
        for (int p = 0; p < 16; p++) {
            float f = fr[p];
            accA[p] = fmaf(wA, f, accA[p]);
            accB[p] = fmaf(wB, f, accB[p]);
            accV[p] = fmaf(wV, f, accV[p]);
        }
    }
#pragma unroll
    for (int p = 0; p < 16; p++) {
        int dst = (b << 13) + rank[pt0 + p];     // wave-uniform scalar
        F1[(size_t)dst * 64 + lane] = accA[p];
        F2[(size_t)dst * 64 + lane] = accB[p];
        FV[(size_t)dst * 64 + lane] = accV[p];
    }
}

// BN stats pass. XCD-swizzled; block partials to PH (NO contended atomics).
__global__ __launch_bounds__(256) void k_hv(
    const float4* __restrict__ sx4, const int* __restrict__ idx,
    const float* __restrict__ F1, const float* __restrict__ F2, const float* __restrict__ FV,
    const float* __restrict__ relw, float* __restrict__ ph)
{
    __shared__ float red[4][4][64];
    int t = threadIdx.x;
    int lane = t & 63;
    int wl = t >> 6;
    int bx = blockIdx.x;                       // 2048 blocks
    int vb = (bx & 7) * 256 + (bx >> 3);       // XCD-aware swizzle
    float rw0 = relw[0 * 64 + lane], rw1 = relw[1 * 64 + lane], rw2 = relw[2 * 64 + lane];
    float rw3 = relw[3 * 64 + lane], rw4 = relw[4 * 64 + lane], rw5 = relw[5 * 64 + lane];
    float sh = 0.f, sh2 = 0.f, sv = 0.f, sv2 = 0.f;
    for (int i = 0; i < 4; i++) {
        int gq = __builtin_amdgcn_readfirstlane(vb * 16 + wl * 4 + i);  // contiguous
        int b = gq >> 13;
        const float4* sb = sx4 + ((size_t)b << 13);
        float4 me = sb[gq & 8191];
        float F1v = F1[(size_t)gq * 64 + lane];
        const int* ip = idx + (size_t)gq * 16;
#pragma unroll
        for (int kb = 0; kb < 2; kb++) {
            float4 cjA[8]; float f2A[8], fvA[8];
#pragma unroll
            for (int j = 0; j < 8; j++) {
                int gl = ip[kb * 8 + j];
                cjA[j] = sb[gl];
                size_t go = (size_t)((b << 13) + gl) * 64 + lane;
                f2A[j] = F2[go];
                fvA[j] = FV[go];
            }
#pragma unroll
            for (int j = 0; j < 8; j++) {
                float rx = cjA[j].x - me.x, ry = cjA[j].y - me.y, rz = cjA[j].z - me.z;
                float h = F1v + f2A[j];
                h = fmaf(rw0, rx, h); h = fmaf(rw1, ry, h); h = fmaf(rw2, rz, h);
                float v = fvA[j];
                v = fmaf(rw3, rx, v); v = fmaf(rw4, ry, v); v = fmaf(rw5, rz, v);
                sh += h; sh2 = fmaf(h, h, sh2);
                sv += v; sv2 = fmaf(v, v, sv2);
            }
        }
    }
    red[0][wl][lane] = sh; red[1][wl][lane] = sh2;
    red[2][wl][lane] = sv; red[3][wl][lane] = sv2;
    __syncthreads();
    float s = red[wl][0][lane] + red[wl][1][lane] + red[wl][2][lane] + red[wl][3][lane];
    ph[(size_t)bx * 256 + wl * 64 + lane] = s;     // plain store, no contention
}

// Reduce PH -> stats[0..255]. 32 blocks x 64 rows each; light atomics (32/addr).
__global__ __launch_bounds__(256) void k_red1(
    const float* __restrict__ ph, float* __restrict__ stats)
{
    int t = threadIdx.x, p = blockIdx.x;
    float acc = 0.f;
    for (int i = 0; i < 64; i++)
        acc += ph[(size_t)(p * 64 + i) * 256 + t];
    atomicAdd(&stats[t], acc);
}

// Attention in SORTED space, XCD-swizzled. Barrier-free, atomic-free, LDS-free.
__global__ __launch_bounds__(256) void k_attn(
    const float4* __restrict__ sx4,
    const int* __restrict__ idx,
    const float* __restrict__ F1, const float* __restrict__ F2, const float* __restrict__ FV,
    const float* __restrict__ relw, const float* __restrict__ stats,
    const float* __restrict__ g1, const float* __restrict__ be1,
    const float* __restrict__ W2, const float* __restrict__ b2,
    const float* __restrict__ gv, const float* __restrict__ bev,
    float* __restrict__ outv)
{
    int t = threadIdx.x;
    int lane = t & 63;
    int wl = t >> 6;
    int bx = blockIdx.x;                      // 8192 blocks
    int vb = (bx & 7) * 1024 + (bx >> 3);     // XCD-aware swizzle
    int gq = vb * 4 + wl;                     // sorted-global query
    const float invM = 1.f / 524288.f;
    float hm = stats[lane] * invM, hq = stats[64 + lane] * invM;
    float s1 = g1[lane] * rsqrtf(hq - hm * hm + EPSBN);
    float t1 = be1[lane] - s1 * hm;
    float vm = stats[128 + lane] * invM, vq = stats[192 + lane] * invM;
    float sv = gv[lane] * rsqrtf(vq - vm * vm + EPSBN);
    float tv = bev[lane] - sv * vm;
    float rw0 = relw[0 * 64 + lane], rw1 = relw[1 * 64 + lane], rw2 = relw[2 * 64 + lane];
    float rw3 = relw[3 * 64 + lane], rw4 = relw[4 * 64 + lane], rw5 = relw[5 * 64 + lane];
    float w2v = W2[lane];
    float b2v = b2[0];

    int b = __builtin_amdgcn_readfirstlane(gq >> 13);
    const float4* sb = sx4 + ((size_t)b << 13);
    float4 me = sb[gq & 8191];
    float F1v = F1[(size_t)gq * 64 + lane];
    const int* ip = idx + (size_t)gq * 16;
    float ek[16], vk[16];
#pragma unroll
    for (int kb = 0; kb < 2; kb++) {
        float4 cjA[8]; float f2A[8], fvA[8];
#pragma unroll
        for (int j = 0; j < 8; j++) {
            int gl = ip[kb * 8 + j];
            cjA[j] = sb[gl];
            size_t go = (size_t)((b << 13) + gl) * 64 + lane;
            f2A[j] = F2[go];
            fvA[j] = FV[go];
        }
#pragma unroll
        for (int j = 0; j < 8; j++) {
            int k = kb * 8 + j;
            float rx = cjA[j].x - me.x, ry = cjA[j].y - me.y, rz = cjA[j].z - me.z;
            float h = F1v + f2A[j];
            h = fmaf(rw0, rx, h); h = fmaf(rw1, ry, h); h = fmaf(rw2, rz, h);
            float a = fmaxf(fmaf(s1, h, t1), 0.f);
            float v = fvA[j];
            v = fmaf(rw3, rx, v); v = fmaf(rw4, ry, v); v = fmaf(rw5, rz, v);
            vk[k] = fmaxf(fmaf(sv, v, tv), 0.f);
            float lg = w2v * a;
#pragma unroll
            for (int off = 32; off >= 1; off >>= 1) lg += __shfl_xor(lg, off, 64);
            ek[k] = lg + b2v;
        }
    }
    float mx = ek[0];
#pragma unroll
    for (int k = 1; k < 16; k++) mx = fmaxf(mx, ek[k]);
    float ssum = 0.f;
#pragma unroll
    for (int k = 0; k < 16; k++) { float e = __expf(ek[k] - mx); ek[k] = e; ssum += e; }
    float acc = 0.f;
#pragma unroll
    for (int k = 0; k < 16; k++) acc = fmaf(ek[k], vk[k], acc);
    outv[(size_t)gq * 64 + lane] = acc / ssum;
}

// Wo matvec + o-stats: out rows (sorted) -> o_pre rows (ORIGINAL layout) + PO partials.
__global__ __launch_bounds__(256) void k_o(
    const float* __restrict__ outv, const float* __restrict__ pwoT,
    const float* __restrict__ bo, const int* __restrict__ sid,
    float* __restrict__ opre, float* __restrict__ po)
{
    __shared__ float red[2][4][64];
    int t = threadIdx.x;
    int lane = t & 63;
    int wl = t >> 6;
    int gq0 = blockIdx.x * 64 + wl * 16;       // 16 sorted points per wave
    int b = __builtin_amdgcn_readfirstlane(gq0 >> 13);
    float acc[16];
    float bov = bo[lane];
#pragma unroll
    for (int p = 0; p < 16; p++) acc[p] = bov;
    for (int c = 0; c < 64; c++) {
        float w = pwoT[c * 64 + lane];
        const float* orow = outv + (size_t)gq0 * 64 + c;
#pragma unroll
        for (int p = 0; p < 16; p++)
            acc[p] = fmaf(w, orow[p * 64], acc[p]);
    }
    float so = 0.f, so2 = 0.f;
#pragma unroll
    for (int p = 0; p < 16; p++) {
        int orig = (b << 13) + sid[gq0 + p];   // wave-uniform scalar
        opre[(size_t)orig * 64 + lane] = acc[p];
        so += acc[p]; so2 = fmaf(acc[p], acc[p], so2);
    }
    red[0][wl][lane] = so; red[1][wl][lane] = so2;
    __syncthreads();
    if (wl < 2) {
        float s = red[wl][0][lane] + red[wl][1][lane] + red[wl][2][lane] + red[wl][3][lane];
        po[(size_t)blockIdx.x * 128 + wl * 64 + lane] = s;
    }
}

// Reduce PO -> stats[256..383]. 8 blocks x 64 rows; light atomics.
__global__ __launch_bounds__(256) void k_red2(
    const float* __restrict__ po, float* __restrict__ stats)
{
    int t = threadIdx.x, p = blockIdx.x;
    if (t < 128) {
        float acc = 0.f;
        for (int i = 0; i < 64; i++)
            acc += po[(size_t)(p * 64 + i) * 128 + t];
        atomicAdd(&stats[256 + t], acc);
    }
}

// Final: BN(o)+relu + residual feats, transpose [B,N,C]->[B,C,N]
__global__ __launch_bounds__(256) void k_final(
    const float* __restrict__ opre, const float* __restrict__ stats,
    const float* __restrict__ go, const float* __restrict__ beo,
    const float* __restrict__ feats, float* __restrict__ out)
{
    __shared__ float tile[64][65];
    int t = threadIdx.x;
    int blk = blockIdx.x;
    int b = blk >> 7, n0 = (blk & 127) << 6;
#pragma unroll
    for (int i = 0; i < 16; i++) {
        int e = t + i * 256;
        int r = e >> 6, c = e & 63;
        tile[r][c] = opre[((size_t)((b << 13) + n0 + r)) * 64 + c];
    }
    __syncthreads();
    const float invM = 1.f / 32768.f;
    int lane = t & 63, wv = t >> 6;
#pragma unroll
    for (int i = 0; i < 16; i++) {
        int c = wv * 16 + i;
        float om = stats[256 + c] * invM, oq = stats[320 + c] * invM;
        float so = go[c] * rsqrtf(oq - om * om + EPSBN);
        float to = beo[c] - so * om;
        float val = fmaxf(fmaf(so, tile[lane][c], to), 0.f);
        size_t oix = ((size_t)b * 64 + c) * NN + n0 + lane;
        out[oix] = val + feats[oix];
    }
}

extern "C" void kernel_launch(void* const* d_in, const int* in_sizes, int n_in,
                              void* d_out, int out_size, void* d_ws, size_t ws_size,
                              hipStream_t stream)
{
    const float* xyz  = (const float*)d_in[0];
    const float* feats= (const float*)d_in[1];
    const float* W1   = (const float*)d_in[2];
    const float* b1   = (const float*)d_in[3];
    const float* g1   = (const float*)d_in[4];
    const float* be1  = (const float*)d_in[5];
    const float* W2   = (const float*)d_in[6];
    const float* b2   = (const float*)d_in[7];
    const float* Wv   = (const float*)d_in[8];
    const float* bv   = (const float*)d_in[9];
    const float* gv   = (const float*)d_in[10];
    const float* bev  = (const float*)d_in[11];
    const float* Wo   = (const float*)d_in[12];
    const float* bo   = (const float*)d_in[13];
    const float* go   = (const float*)d_in[14];
    const float* beo  = (const float*)d_in[15];

    float* ws = (float*)d_ws;
    float* xyzw  = ws + OFF_XYZW;
    float* pw1aT = ws + OFF_PW1AT;
    float* pw1bT = ws + OFF_PW1BT;
    float* pwvaT = ws + OFF_PWVAT;
    float* pwoT  = ws + OFF_PWOT;
    float* relw  = ws + OFF_RELW;
    float* stats = ws + OFF_STATS;
    int*   idx   = (int*)(ws + OFF_IDX);
    int*   pip   = (int*)(ws + OFF_PIP);
    float* outv  = ws + OFF_OUTV;   // aliases pip (dead after k_refine)
    float4* sx4  = (float4*)(ws + OFF_SX4);
    int*   sid   = (int*)(ws + OFF_SID);
    int*   hist  = (int*)(ws + OFF_HIST);
    float4* bbmn = (float4*)(ws + OFF_BB);
    float4* bbmx = (float4*)(ws + OFF_BB + 2048);
    int*   rank  = (int*)(ws + OFF_RANK);
    float* ph    = ws + OFF_PH;
    float* po    = ws + OFF_PO;
    int*   kc    = (int*)(ws + OFF_KC);
    float* F1    = ws + OFF_F1;
    float* F2    = ws + OFF_F2;
    float* FV    = ws + OFF_FV;
    float* opre  = ws + OFF_OPRE;   // aliases F1 (dead after k_attn)

    k_zero<<<1, 256, 0, stream>>>(hist);
    k_prep<<<129, 256, 0, stream>>>(xyz, W1, Wv, Wo, xyzw, hist,
                                    pw1aT, pw1bT, pwvaT, pwoT, relw, stats);
    k_scan<<<4, 256, 0, stream>>>(hist);
    k_scatter<<<128, 256, 0, stream>>>((const float4*)xyzw, hist, sx4, sid, rank);
    k_bbox<<<128, 256, 0, stream>>>((const float4*)sx4, bbmn, bbmx);
    k_F<<<512, 256, 0, stream>>>(feats, b1, bv, pw1aT, pw1bT, pwvaT, rank, F1, F2, FV);
    k_knn<<<8192, 256, 0, stream>>>((const float4*)sx4, bbmn, bbmx, pip, kc);
    k_refine<<<8192, 256, 0, stream>>>((const float4*)sx4, sid, pip, kc, idx);
    k_hv<<<2048, 256, 0, stream>>>((const float4*)sx4, idx, F1, F2, FV, relw, ph);
    k_red1<<<32, 256, 0, stream>>>(ph, stats);
    k_attn<<<8192, 256, 0, stream>>>((const float4*)sx4, idx, F1, F2, FV, relw, stats,
                                     g1, be1, W2, b2, gv, bev, outv);
    k_o<<<512, 256, 0, stream>>>(outv, pwoT, bo, sid, opre, po);
    k_red2<<<8, 256, 0, stream>>>(po, stats);
    k_final<<<512, 256, 0, stream>>>(opre, stats, go, beo, feats, (float*)d_out);
}

// Round 13
// 321.907 us; speedup vs baseline: 1.3868x; 1.0544x over previous
//
#include <hip/hip_runtime.h>
#include <math.h>

// Problem constants
#define BB 4
#define NN 8192
#define CC 64
#define KK 16
#define HH 64
#define NPTS (BB*NN)   // 32768
#define EPSBN 1e-5f
#define CAP 64         // candidate buffer per query (fp64 refine picks 16)
#define NCELL 4096     // 16^3 Morton cells
#define CHN 128        // chunks per batch
#define CHSZ 64        // points per chunk

// ---------------- ws layout (float offsets) ----------------
#define OFF_XYZW  0
#define OFF_PW1AT 131072
#define OFF_PW1BT 135168
#define OFF_PWVAT 139264
#define OFF_PWOT  143360
#define OFF_RELW  147456
#define OFF_STATS 147840
#define OFF_IDX   148224      // idx: 32768*16 ints (SORTED-space neighbor ids)
#define OFF_OUTV  672512      // [32768][64] sorted attention output
#define OFF_SX4   2769664     // sorted xyzw [4][8192] float4
#define OFF_SID   2900736     // sorted->orig ids [4][8192] int
#define OFF_HIST  2933504     // [4][4096] int
#define OFF_RANK  2950912     // orig->sorted rank [4][8192] int
#define OFF_PH    2983680     // k_hv block partials [2048][256]
#define OFF_PO    3507968     // k_o block partials [512][128]
#define OFF_BB    3606272     // bbmin[512] f4 (2048) + bbmax[512] f4 (2048)
#define OFF_F1    4866816     // SORTED layout (dead after k_attn)
#define OFF_OPRE  4866816     // OPRE aliases F1: [32768][64] original layout
#define OFF_F2    6963968     // SORTED layout
#define OFF_FV    9061120     // SORTED layout

__device__ __forceinline__ int morton_cell(float x, float y, float z) {
    int cx = (int)floorf((x + 4.f) * 2.f);
    int cy = (int)floorf((y + 4.f) * 2.f);
    int cz = (int)floorf((z + 4.f) * 2.f);
    cx = cx < 0 ? 0 : (cx > 15 ? 15 : cx);
    cy = cy < 0 ? 0 : (cy > 15 ? 15 : cy);
    cz = cz < 0 ? 0 : (cz > 15 ? 15 : cz);
    int ex = (cx & 1) | ((cx & 2) << 2) | ((cx & 4) << 4) | ((cx & 8) << 6);
    int ey = (cy & 1) | ((cy & 2) << 2) | ((cy & 4) << 4) | ((cy & 8) << 6);
    int ez = (cz & 1) | ((cz & 2) << 2) | ((cz & 4) << 4) | ((cz & 8) << 6);
    return ex | (ey << 1) | (ez << 2);
}

__device__ __forceinline__ float distf(float4 me, float jx, float jy, float jz, float jw) {
    float dot = fmaf(me.z, jz, fmaf(me.y, jy, me.x * jx));
    return fmaf(-2.f, dot, me.w) + jw;
}

__device__ __forceinline__ float mind2(float4 me, float4 bmin, float4 bmax) {
    float dx = fmaxf(fmaxf(bmin.x - me.x, me.x - bmax.x), 0.f);
    float dy = fmaxf(fmaxf(bmin.y - me.y, me.y - bmax.y), 0.f);
    float dz = fmaxf(fmaxf(bmin.z - me.z, me.z - bmax.z), 0.f);
    return fmaf(dx, dx, fmaf(dy, dy, dz * dz));
}

__device__ __forceinline__ int mbcnt64(unsigned long long m) {
    return __builtin_amdgcn_mbcnt_hi((unsigned int)(m >> 32),
           __builtin_amdgcn_mbcnt_lo((unsigned int)m, 0));
}

__global__ __launch_bounds__(256) void k_prep(
    const float* __restrict__ xyz, const float* __restrict__ W1,
    const float* __restrict__ Wv, const float* __restrict__ Wo,
    float* __restrict__ xyzw, int* __restrict__ hist,
    float* __restrict__ pw1aT, float* __restrict__ pw1bT,
    float* __restrict__ pwvaT, float* __restrict__ pwoT, float* __restrict__ relw,
    float* __restrict__ stats)
{
    int t = threadIdx.x;
    int bid = blockIdx.x;
    if (bid < 128) {
        int pt = bid * 256 + t;
        int b = pt >> 13, n = pt & 8191;
        const float* xb = xyz + (size_t)b * 3 * NN;
        float x = xb[n], y = xb[NN + n], z = xb[2 * NN + n];
        float sq = __fadd_rn(__fadd_rn(__fmul_rn(x, x), __fmul_rn(y, y)), __fmul_rn(z, z));
        ((float4*)xyzw)[pt] = make_float4(x, y, z, sq);
        atomicAdd(&hist[b * NCELL + morton_cell(x, y, z)], 1);
    } else {
        for (int e = t; e < 4096; e += 256) {
            int c = e >> 6, o = e & 63;
            pw1aT[e] = W1[o * 131 + c];
            pw1bT[e] = W1[o * 131 + 64 + c];
            pwvaT[e] = Wv[o * 67 + c];
            pwoT[e]  = Wo[o * 64 + c];
        }
        for (int e = t; e < 384; e += 256) {
            int d = e >> 6, o = e & 63;
            relw[e] = (d < 3) ? W1[o * 131 + 128 + d] : Wv[o * 67 + 64 + (d - 3)];
            stats[e] = 0.0f;
        }
    }
}

// Exclusive scan of per-batch 4096-bin histogram (in place), one block per batch.
__global__ __launch_bounds__(256) void k_scan(int* __restrict__ hist) {
    __shared__ int part[256];
    int b = blockIdx.x, t = threadIdx.x;
    int* h = hist + b * NCELL;
    int loc[16]; int s = 0;
#pragma unroll
    for (int i = 0; i < 16; i++) { loc[i] = h[t * 16 + i]; s += loc[i]; }
    part[t] = s;
    __syncthreads();
    for (int off = 1; off < 256; off <<= 1) {
        int v = (t >= off) ? part[t - off] : 0;
        __syncthreads();
        part[t] += v;
        __syncthreads();
    }
    int run = (t > 0) ? part[t - 1] : 0;
#pragma unroll
    for (int i = 0; i < 16; i++) { int c = loc[i]; h[t * 16 + i] = run; run += c; }
}

__global__ __launch_bounds__(256) void k_scatter(
    const float4* __restrict__ xyzw, int* __restrict__ off,
    float4* __restrict__ sx4, int* __restrict__ sid, int* __restrict__ rank)
{
    int pt = blockIdx.x * 256 + threadIdx.x;
    int b = pt >> 13, n = pt & 8191;
    float4 p = xyzw[pt];
    int cell = morton_cell(p.x, p.y, p.z);
    int dst = atomicAdd(&off[b * NCELL + cell], 1);
    sx4[(b << 13) + dst] = p;
    sid[(b << 13) + dst] = n;
    rank[pt] = dst;
}

// Per-chunk bbox over 64 sorted points. One wave per chunk; 512 chunks total.
__global__ __launch_bounds__(256) void k_bbox(
    const float4* __restrict__ sx4, float4* __restrict__ bbmin, float4* __restrict__ bbmax)
{
    int t = threadIdx.x, lane = t & 63, wl = t >> 6;
    int ch = blockIdx.x * 4 + wl;             // 0..511
    float4 p = sx4[ch * CHSZ + lane];
    float mnx = p.x, mny = p.y, mnz = p.z, mxx = p.x, mxy = p.y, mxz = p.z;
#pragma unroll
    for (int o = 32; o >= 1; o >>= 1) {
        mnx = fminf(mnx, __shfl_xor(mnx, o, 64)); mxx = fmaxf(mxx, __shfl_xor(mxx, o, 64));
        mny = fminf(mny, __shfl_xor(mny, o, 64)); mxy = fmaxf(mxy, __shfl_xor(mxy, o, 64));
        mnz = fminf(mnz, __shfl_xor(mnz, o, 64)); mxz = fmaxf(mxz, __shfl_xor(mxz, o, 64));
    }
    if (lane == 0) {
        bbmin[ch] = make_float4(mnx, mny, mnz, 0.f);
        bbmax[ch] = make_float4(mxx, mxy, mxz, 0.f);
    }
}

// Fused KNN + fp64 refine. One query per 64-thread block (one wave).
// Window sort -> tau = 16th-best (+margin). Chunk mask over 128 tight 64-pt
// chunks; software-pipelined chunk scan (prefetch next chunk's load before
// processing current) appends hits to a per-wave LDS buffer via ballot+mbcnt.
// Rare overflow -> verified sorted-insert top-32. Then lane c computes the
// fp64 distance of candidate c and a wave bitonic sort on (d, orig_idx)
// (exact total order) yields idx[0..15] directly.
__global__ __launch_bounds__(64) void k_knn(
    const float4* __restrict__ sx4, const int* __restrict__ sid,
    const float4* __restrict__ bbmin, const float4* __restrict__ bbmax,
    int* __restrict__ idx)
{
    __shared__ int cand[CAP];
    int lane = threadIdx.x;
    int gq = blockIdx.x;
    int b = __builtin_amdgcn_readfirstlane(gq >> 13);
    int qs = gq & 8191;
    const float4* sb = sx4 + ((size_t)b << 13);
    const int* ib = sid + ((size_t)b << 13);
    float4 me = sb[qs];                       // wave-uniform
    const float INF = 3.402823466e38f;

    // phase 1: bitonic-sort the 64-point positional window
    int ws0 = qs - 32; ws0 = ws0 < 0 ? 0 : (ws0 > (NN - 64) ? (NN - 64) : ws0);
    float4 cp = sb[ws0 + lane];
    int cid = ws0 + lane;                     // sorted-space id
    float d = distf(me, cp.x, cp.y, cp.z, cp.w);
#pragma unroll
    for (int k2 = 2; k2 <= 64; k2 <<= 1) {
#pragma unroll
        for (int j2 = k2 >> 1; j2 >= 1; j2 >>= 1) {
            float od = __shfl_xor(d, j2, 64);
            int   oi = __shfl_xor(cid, j2, 64);
            bool up = ((lane & k2) == 0);
            bool lower = ((lane & j2) == 0);
            bool wantMin = (lower == up);
            bool to = wantMin ? (od < d) : (od > d);
            d = to ? od : d; cid = to ? oi : cid;
        }
    }
    // tau from the 16th smallest: superset of fp64 top-16 guaranteed.
    float tau = __int_as_float(__builtin_amdgcn_readlane(__float_as_int(d), 15));
    float tauA = tau * 1.0001f + 1e-5f;

    // chunk masks (evaluated once; reused by fallback with larger tau)
    float md0 = mind2(me, bbmin[b * CHN + lane], bbmax[b * CHN + lane]);
    float md1 = mind2(me, bbmin[b * CHN + 64 + lane], bbmax[b * CHN + 64 + lane]);

    int cnt;
    {
        bool hit = (d <= tauA);
        unsigned long long hm = __ballot(hit);
        if (hit) cand[mbcnt64(hm)] = cid;
        cnt = __popcll(hm);

        unsigned long long bm0 = __ballot(md0 <= tauA);
        unsigned long long bm1 = __ballot(md1 <= tauA);

        // software-pipelined chunk scan (prefetch depth 2)
        int c0 = -1;
        if (bm0)      { c0 = __builtin_ctzll(bm0); bm0 &= bm0 - 1; }
        else if (bm1) { c0 = 64 + __builtin_ctzll(bm1); bm1 &= bm1 - 1; }
        float4 p0 = make_float4(0.f, 0.f, 0.f, 0.f);
        if (c0 >= 0) p0 = sb[c0 * CHSZ + lane];
        while (c0 >= 0) {
            int c1 = -1;
            if (bm0)      { c1 = __builtin_ctzll(bm0); bm0 &= bm0 - 1; }
            else if (bm1) { c1 = 64 + __builtin_ctzll(bm1); bm1 &= bm1 - 1; }
            float4 p1 = p0;
            if (c1 >= 0) p1 = sb[c1 * CHSZ + lane];   // issued before ballots below
            int pos = c0 * CHSZ + lane;
            float dd = distf(me, p0.x, p0.y, p0.z, p0.w);
            bool inwin = (pos >= ws0) && (pos < ws0 + 64);
            bool hit2 = (dd <= tauA) && !inwin;
            unsigned long long m2 = __ballot(hit2);
            if (hit2) {
                int slot = cnt + mbcnt64(m2);
                if (slot < CAP) cand[slot] = pos;
            }
            cnt += __popcll(m2);
            c0 = c1; p0 = p1;
        }
    }

    if (cnt > CAP) {
        // ---- rare fallback: verified sorted-insert top-32 (window-seeded) ----
        bool lt32 = (lane < 32);
        float val = lt32 ? d : INF;
        int vid = cid;
        float tau2 = __int_as_float(__builtin_amdgcn_readlane(__float_as_int(val), 31));
        float t2A = tau2 * 1.0001f + 1e-5f;
        unsigned long long fb0 = __ballot(md0 <= t2A);
        unsigned long long fb1 = __ballot(md1 <= t2A);
        while (fb0 | fb1) {
            int c;
            if (fb0) { c = __builtin_ctzll(fb0); fb0 &= fb0 - 1; }
            else     { c = 64 + __builtin_ctzll(fb1); fb1 &= fb1 - 1; }
            int pos = c * CHSZ + lane;
            float4 p = sb[pos];
            float dd = distf(me, p.x, p.y, p.z, p.w);
            bool inwin = (pos >= ws0) && (pos < ws0 + 64);
            dd = inwin ? INF : dd;
            unsigned long long m = __ballot(dd < tau2);
            while (m) {
                int hl = __builtin_ctzll(m); m &= m - 1;
                float dn = __int_as_float(
                    __builtin_amdgcn_readlane(__float_as_int(dd), hl));
                int jn = c * CHSZ + hl;
                unsigned long long bl = __ballot(val < dn);
                int pos2 = __popcll(bl);
                float sv = __shfl_up(val, 1, 64);
                int   sj = __shfl_up(vid, 1, 64);
                float nv = (lane > pos2) ? sv : val; nv = (lane == pos2) ? dn : nv;
                int   nj = (lane > pos2) ? sj : vid; nj = (lane == pos2) ? jn : nj;
                val = lt32 ? nv : val;
                vid = lt32 ? nj : vid;
                tau2 = __int_as_float(__builtin_amdgcn_readlane(__float_as_int(val), 31));
            }
        }
        if (lt32) cand[lane] = vid;
        cnt = 32;
    }

    // ---- merged fp64 refine: lane c = candidate c; bitonic (dd, oj) ----
    double mx = (double)me.x, my = (double)me.y, mz = (double)me.z;
    double msq = (mx * mx + my * my) + mz * mz;
    int j = 0, oj = 0x40000000 + lane;        // unique sentinel > any valid oj
    double dd = 1e300;
    if (lane < cnt) {
        j = cand[lane];
        float4 cj = sb[j];
        oj = ib[j];
        double jx = (double)cj.x, jy = (double)cj.y, jz = (double)cj.z;
        double dot = (mx * jx + my * jy) + mz * jz;
        double sqj = (jx * jx + jy * jy) + jz * jz;
        dd = (-2.0 * dot + msq) + sqj;
    }
#pragma unroll
    for (int k2 = 2; k2 <= 64; k2 <<= 1) {
#pragma unroll
        for (int j2 = k2 >> 1; j2 >= 1; j2 >>= 1) {
            double od = __shfl_xor(dd, j2, 64);
            int   ooj = __shfl_xor(oj, j2, 64);
            int   oid = __shfl_xor(j, j2, 64);
            bool up = ((lane & k2) == 0);
            bool lower = ((lane & j2) == 0);
            bool wantMin = (lower == up);
            bool oless = (od < dd) || (od == dd && ooj < oj);
            bool take = wantMin ? oless : !oless;
            dd = take ? od : dd; oj = take ? ooj : oj; j = take ? oid : j;
        }
    }
    if (lane < 16) idx[(size_t)gq * 16 + lane] = j;
}

// Per-point GEMVs, output scattered to SORTED layout via rank.
__global__ __launch_bounds__(256) void k_F(
    const float* __restrict__ feats, const float* __restrict__ b1, const float* __restrict__ bv,
    const float* __restrict__ pw1aT, const float* __restrict__ pw1bT, const float* __restrict__ pwvaT,
    const int* __restrict__ rank,
    float* __restrict__ F1, float* __restrict__ F2, float* __restrict__ FV)
{
    int t = threadIdx.x;
    int lane = t & 63;
    int wave = t >> 6;
    int pt0 = blockIdx.x * 64 + wave * 16;
    int b   = __builtin_amdgcn_readfirstlane(pt0 >> 13);
    int n0  = __builtin_amdgcn_readfirstlane(pt0 & 8191);
    const float* fb = feats + (size_t)b * CC * NN;
    float accA[16], accB[16], accV[16];
    float bb1 = b1[lane], bbv = bv[lane];
#pragma unroll
    for (int p = 0; p < 16; p++) { accA[p] = bb1; accB[p] = 0.f; accV[p] = bbv; }
    for (int c = 0; c < 64; c++) {
        float wA = pw1aT[c * 64 + lane];
        float wB = pw1bT[c * 64 + lane];
        float wV = pwvaT[c * 64 + lane];
        const float* fr = fb + (size_t)c * NN + n0;
#pragma unroll
        for (int p = 0; p < 16; p++) {
            float f = fr[p];
            accA[p] = fmaf(wA, f, accA[p]);
            accB[p] = fmaf(wB, f, accB[p]);
            accV[p] = fmaf(wV, f, accV[p]);
        }
    }
#pragma unroll
    for (int p = 0; p < 16; p++) {
        int dst = (b << 13) + rank[pt0 + p];     // wave-uniform scalar
        F1[(size_t)dst * 64 + lane] = accA[p];
        F2[(size_t)dst * 64 + lane] = accB[p];
        FV[(size_t)dst * 64 + lane] = accV[p];
    }
}

// BN stats pass. XCD-swizzled; block partials to PH (NO contended atomics).
__global__ __launch_bounds__(256) void k_hv(
    const float4* __restrict__ sx4, const int* __restrict__ idx,
    const float* __restrict__ F1, const float* __restrict__ F2, const float* __restrict__ FV,
    const float* __restrict__ relw, float* __restrict__ ph)
{
    __shared__ float red[4][4][64];
    int t = threadIdx.x;
    int lane = t & 63;
    int wl = t >> 6;
    int bx = blockIdx.x;                       // 2048 blocks
    int vb = (bx & 7) * 256 + (bx >> 3);       // XCD-aware swizzle
    float rw0 = relw[0 * 64 + lane], rw1 = relw[1 * 64 + lane], rw2 = relw[2 * 64 + lane];
    float rw3 = relw[3 * 64 + lane], rw4 = relw[4 * 64 + lane], rw5 = relw[5 * 64 + lane];
    float sh = 0.f, sh2 = 0.f, sv = 0.f, sv2 = 0.f;
    for (int i = 0; i < 4; i++) {
        int gq = __builtin_amdgcn_readfirstlane(vb * 16 + wl * 4 + i);  // contiguous
        int b = gq >> 13;
        const float4* sb = sx4 + ((size_t)b << 13);
        float4 me = sb[gq & 8191];
        float F1v = F1[(size_t)gq * 64 + lane];
        const int* ip = idx + (size_t)gq * 16;
#pragma unroll
        for (int kb = 0; kb < 2; kb++) {
            float4 cjA[8]; float f2A[8], fvA[8];
#pragma unroll
            for (int j = 0; j < 8; j++) {
                int gl = ip[kb * 8 + j];
                cjA[j] = sb[gl];
                size_t go = (size_t)((b << 13) + gl) * 64 + lane;
                f2A[j] = F2[go];
                fvA[j] = FV[go];
            }
#pragma unroll
            for (int j = 0; j < 8; j++) {
                float rx = cjA[j].x - me.x, ry = cjA[j].y - me.y, rz = cjA[j].z - me.z;
                float h = F1v + f2A[j];
                h = fmaf(rw0, rx, h); h = fmaf(rw1, ry, h); h = fmaf(rw2, rz, h);
                float v = fvA[j];
                v = fmaf(rw3, rx, v); v = fmaf(rw4, ry, v); v = fmaf(rw5, rz, v);
                sh += h; sh2 = fmaf(h, h, sh2);
                sv += v; sv2 = fmaf(v, v, sv2);
            }
        }
    }
    red[0][wl][lane] = sh; red[1][wl][lane] = sh2;
    red[2][wl][lane] = sv; red[3][wl][lane] = sv2;
    __syncthreads();
    float s = red[wl][0][lane] + red[wl][1][lane] + red[wl][2][lane] + red[wl][3][lane];
    ph[(size_t)bx * 256 + wl * 64 + lane] = s;     // plain store, no contention
}

// Reduce PH -> stats[0..255]. 32 blocks x 64 rows each; light atomics (32/addr).
__global__ __launch_bounds__(256) void k_red1(
    const float* __restrict__ ph, float* __restrict__ stats)
{
    int t = threadIdx.x, p = blockIdx.x;
    float acc = 0.f;
    for (int i = 0; i < 64; i++)
        acc += ph[(size_t)(p * 64 + i) * 256 + t];
    atomicAdd(&stats[t], acc);
}

// Attention in SORTED space, XCD-swizzled. Barrier-free, atomic-free, LDS-free.
__global__ __launch_bounds__(256) void k_attn(
    const float4* __restrict__ sx4,
    const int* __restrict__ idx,
    const float* __restrict__ F1, const float* __restrict__ F2, const float* __restrict__ FV,
    const float* __restrict__ relw, const float* __restrict__ stats,
    const float* __restrict__ g1, const float* __restrict__ be1,
    const float* __restrict__ W2, const float* __restrict__ b2,
    const float* __restrict__ gv, const float* __restrict__ bev,
    float* __restrict__ outv)
{
    int t = threadIdx.x;
    int lane = t & 63;
    int wl = t >> 6;
    int bx = blockIdx.x;                      // 8192 blocks
    int vb = (bx & 7) * 1024 + (bx >> 3);     // XCD-aware swizzle
    int gq = vb * 4 + wl;                     // sorted-global query
    const float invM = 1.f / 524288.f;
    float hm = stats[lane] * invM, hq = stats[64 + lane] * invM;
    float s1 = g1[lane] * rsqrtf(hq - hm * hm + EPSBN);
    float t1 = be1[lane] - s1 * hm;
    float vm = stats[128 + lane] * invM, vq = stats[192 + lane] * invM;
    float sv = gv[lane] * rsqrtf(vq - vm * vm + EPSBN);
    float tv = bev[lane] - sv * vm;
    float rw0 = relw[0 * 64 + lane], rw1 = relw[1 * 64 + lane], rw2 = relw[2 * 64 + lane];
    float rw3 = relw[3 * 64 + lane], rw4 = relw[4 * 64 + lane], rw5 = relw[5 * 64 + lane];
    float w2v = W2[lane];
    float b2v = b2[0];

    int b = __builtin_amdgcn_readfirstlane(gq >> 13);
    const float4* sb = sx4 + ((size_t)b << 13);
    float4 me = sb[gq & 8191];
    float F1v = F1[(size_t)gq * 64 + lane];
    const int* ip = idx + (size_t)gq * 16;
    float ek[16], vk[16];
#pragma unroll
    for (int kb = 0; kb < 2; kb++) {
        float4 cjA[8]; float f2A[8], fvA[8];
#pragma unroll
        for (int j = 0; j < 8; j++) {
            int gl = ip[kb * 8 + j];
            cjA[j] = sb[gl];
            size_t go = (size_t)((b << 13) + gl) * 64 + lane;
            f2A[j] = F2[go];
            fvA[j] = FV[go];
        }
#pragma unroll
        for (int j = 0; j < 8; j++) {
            int k = kb * 8 + j;
            float rx = cjA[j].x - me.x, ry = cjA[j].y - me.y, rz = cjA[j].z - me.z;
            float h = F1v + f2A[j];
            h = fmaf(rw0, rx, h); h = fmaf(rw1, ry, h); h = fmaf(rw2, rz, h);
            float a = fmaxf(fmaf(s1, h, t1), 0.f);
            float v = fvA[j];
            v = fmaf(rw3, rx, v); v = fmaf(rw4, ry, v); v = fmaf(rw5, rz, v);
            vk[k] = fmaxf(fmaf(sv, v, tv), 0.f);
            float lg = w2v * a;
#pragma unroll
            for (int off = 32; off >= 1; off >>= 1) lg += __shfl_xor(lg, off, 64);
            ek[k] = lg + b2v;
        }
    }
    float mx = ek[0];
#pragma unroll
    for (int k = 1; k < 16; k++) mx = fmaxf(mx, ek[k]);
    float ssum = 0.f;
#pragma unroll
    for (int k = 0; k < 16; k++) { float e = __expf(ek[k] - mx); ek[k] = e; ssum += e; }
    float acc = 0.f;
#pragma unroll
    for (int k = 0; k < 16; k++) acc = fmaf(ek[k], vk[k], acc);
    outv[(size_t)gq * 64 + lane] = acc / ssum;
}

// Wo matvec + o-stats: out rows (sorted) -> o_pre rows (ORIGINAL layout) + PO partials.
__global__ __launch_bounds__(256) void k_o(
    const float* __restrict__ outv, const float* __restrict__ pwoT,
    const float* __restrict__ bo, const int* __restrict__ sid,
    float* __restrict__ opre, float* __restrict__ po)
{
    __shared__ float red[2][4][64];
    int t = threadIdx.x;
    int lane = t & 63;
    int wl = t >> 6;
    int gq0 = blockIdx.x * 64 + wl * 16;       // 16 sorted points per wave
    int b = __builtin_amdgcn_readfirstlane(gq0 >> 13);
    float acc[16];
    float bov = bo[lane];
#pragma unroll
    for (int p = 0; p < 16; p++) acc[p] = bov;
    for (int c = 0; c < 64; c++) {
        float w = pwoT[c * 64 + lane];
        const float* orow = outv + (size_t)gq0 * 64 + c;
#pragma unroll
        for (int p = 0; p < 16; p++)
            acc[p] = fmaf(w, orow[p * 64], acc[p]);
    }
    float so = 0.f, so2 = 0.f;
#pragma unroll
    for (int p = 0; p < 16; p++) {
        int orig = (b << 13) + sid[gq0 + p];   // wave-uniform scalar
        opre[(size_t)orig * 64 + lane] = acc[p];
        so += acc[p]; so2 = fmaf(acc[p], acc[p], so2);
    }
    red[0][wl][lane] = so; red[1][wl][lane] = so2;
    __syncthreads();
    if (wl < 2) {
        float s = red[wl][0][lane] + red[wl][1][lane] + red[wl][2][lane] + red[wl][3][lane];
        po[(size_t)blockIdx.x * 128 + wl * 64 + lane] = s;
    }
}

// Reduce PO -> stats[256..383]. 8 blocks x 64 rows; light atomics.
__global__ __launch_bounds__(256) void k_red2(
    const float* __restrict__ po, float* __restrict__ stats)
{
    int t = threadIdx.x, p = blockIdx.x;
    if (t < 128) {
        float acc = 0.f;
        for (int i = 0; i < 64; i++)
            acc += po[(size_t)(p * 64 + i) * 128 + t];
        atomicAdd(&stats[256 + t], acc);
    }
}

// Final: BN(o)+relu + residual feats, transpose [B,N,C]->[B,C,N]
__global__ __launch_bounds__(256) void k_final(
    const float* __restrict__ opre, const float* __restrict__ stats,
    const float* __restrict__ go, const float* __restrict__ beo,
    const float* __restrict__ feats, float* __restrict__ out)
{
    __shared__ float tile[64][65];
    int t = threadIdx.x;
    int blk = blockIdx.x;
    int b = blk >> 7, n0 = (blk & 127) << 6;
#pragma unroll
    for (int i = 0; i < 16; i++) {
        int e = t + i * 256;
        int r = e >> 6, c = e & 63;
        tile[r][c] = opre[((size_t)((b << 13) + n0 + r)) * 64 + c];
    }
    __syncthreads();
    const float invM = 1.f / 32768.f;
    int lane = t & 63, wv = t >> 6;
#pragma unroll
    for (int i = 0; i < 16; i++) {
        int c = wv * 16 + i;
        float om = stats[256 + c] * invM, oq = stats[320 + c] * invM;
        float so = go[c] * rsqrtf(oq - om * om + EPSBN);
        float to = beo[c] - so * om;
        float val = fmaxf(fmaf(so, tile[lane][c], to), 0.f);
        size_t oix = ((size_t)b * 64 + c) * NN + n0 + lane;
        out[oix] = val + feats[oix];
    }
}

extern "C" void kernel_launch(void* const* d_in, const int* in_sizes, int n_in,
                              void* d_out, int out_size, void* d_ws, size_t ws_size,
                              hipStream_t stream)
{
    const float* xyz  = (const float*)d_in[0];
    const float* feats= (const float*)d_in[1];
    const float* W1   = (const float*)d_in[2];
    const float* b1   = (const float*)d_in[3];
    const float* g1   = (const float*)d_in[4];
    const float* be1  = (const float*)d_in[5];
    const float* W2   = (const float*)d_in[6];
    const float* b2   = (const float*)d_in[7];
    const float* Wv   = (const float*)d_in[8];
    const float* bv   = (const float*)d_in[9];
    const float* gv   = (const float*)d_in[10];
    const float* bev  = (const float*)d_in[11];
    const float* Wo   = (const float*)d_in[12];
    const float* bo   = (const float*)d_in[13];
    const float* go   = (const float*)d_in[14];
    const float* beo  = (const float*)d_in[15];

    float* ws = (float*)d_ws;
    float* xyzw  = ws + OFF_XYZW;
    float* pw1aT = ws + OFF_PW1AT;
    float* pw1bT = ws + OFF_PW1BT;
    float* pwvaT = ws + OFF_PWVAT;
    float* pwoT  = ws + OFF_PWOT;
    float* relw  = ws + OFF_RELW;
    float* stats = ws + OFF_STATS;
    int*   idx   = (int*)(ws + OFF_IDX);
    float* outv  = ws + OFF_OUTV;
    float4* sx4  = (float4*)(ws + OFF_SX4);
    int*   sid   = (int*)(ws + OFF_SID);
    int*   hist  = (int*)(ws + OFF_HIST);
    float4* bbmn = (float4*)(ws + OFF_BB);
    float4* bbmx = (float4*)(ws + OFF_BB + 2048);
    int*   rank  = (int*)(ws + OFF_RANK);
    float* ph    = ws + OFF_PH;
    float* po    = ws + OFF_PO;
    float* F1    = ws + OFF_F1;
    float* F2    = ws + OFF_F2;
    float* FV    = ws + OFF_FV;
    float* opre  = ws + OFF_OPRE;   // aliases F1 (dead after k_attn)

    hipMemsetAsync(hist, 0, BB * NCELL * sizeof(int), stream);
    k_prep<<<129, 256, 0, stream>>>(xyz, W1, Wv, Wo, xyzw, hist,
                                    pw1aT, pw1bT, pwvaT, pwoT, relw, stats);
    k_scan<<<4, 256, 0, stream>>>(hist);
    k_scatter<<<128, 256, 0, stream>>>((const float4*)xyzw, hist, sx4, sid, rank);
    k_bbox<<<128, 256, 0, stream>>>((const float4*)sx4, bbmn, bbmx);
    k_F<<<512, 256, 0, stream>>>(feats, b1, bv, pw1aT, pw1bT, pwvaT, rank, F1, F2, FV);
    k_knn<<<NPTS, 64, 0, stream>>>((const float4*)sx4, sid, bbmn, bbmx, idx);
    k_hv<<<2048, 256, 0, stream>>>((const float4*)sx4, idx, F1, F2, FV, relw, ph);
    k_red1<<<32, 256, 0, stream>>>(ph, stats);
    k_attn<<<8192, 256, 0, stream>>>((const float4*)sx4, idx, F1, F2, FV, relw, stats,
                                     g1, be1, W2, b2, gv, bev, outv);
    k_o<<<512, 256, 0, stream>>>(outv, pwoT, bo, sid, opre, po);
    k_red2<<<8, 256, 0, stream>>>(po, stats);
    k_final<<<512, 256, 0, stream>>>(opre, stats, go, beo, feats, (float*)d_out);
}

// Round 14
// 317.772 us; speedup vs baseline: 1.4049x; 1.0130x over previous
//
#include <hip/hip_runtime.h>
#include <math.h>

// Problem constants
#define BB 4
#define NN 8192
#define CC 64
#define KK 16
#define HH 64
#define NPTS (BB*NN)   // 32768
#define EPSBN 1e-5f
#define CAP 64         // candidate buffer per query (fp64 refine picks 16)
#define NCELL 4096     // 16^3 Morton cells
#define CHN 128        // chunks per batch
#define CHSZ 64        // points per chunk

// ---------------- ws layout (float offsets) ----------------
#define OFF_XYZW  0
#define OFF_PW1AT 131072
#define OFF_PW1BT 135168
#define OFF_PWVAT 139264
#define OFF_PWOT  143360
#define OFF_RELW  147456
#define OFF_STATS 147840
#define OFF_IDX   148224      // idx: 32768*16 ints (SORTED-space neighbor ids)
#define OFF_OUTV  672512      // [32768][64] sorted attention output
#define OFF_SX4   2769664     // sorted xyzw [4][8192] float4
#define OFF_SID   2900736     // sorted->orig ids [4][8192] int
#define OFF_HIST  2933504     // [4][4096] int
#define OFF_RANK  2950912     // orig->sorted rank [4][8192] int
#define OFF_PH    2983680     // k_hv block partials [2048][256]
#define OFF_PO    3507968     // k_o block partials [512][128]
#define OFF_BB    3606272     // bbmin[512] f4 (2048) + bbmax[512] f4 (2048)
#define OFF_F1    4866816     // SORTED layout (dead after k_attn)
#define OFF_OPRE  4866816     // OPRE aliases F1: [32768][64] original layout
#define OFF_F2    6963968     // SORTED layout
#define OFF_FV    9061120     // SORTED layout

__device__ __forceinline__ int morton_cell(float x, float y, float z) {
    int cx = (int)floorf((x + 4.f) * 2.f);
    int cy = (int)floorf((y + 4.f) * 2.f);
    int cz = (int)floorf((z + 4.f) * 2.f);
    cx = cx < 0 ? 0 : (cx > 15 ? 15 : cx);
    cy = cy < 0 ? 0 : (cy > 15 ? 15 : cy);
    cz = cz < 0 ? 0 : (cz > 15 ? 15 : cz);
    int ex = (cx & 1) | ((cx & 2) << 2) | ((cx & 4) << 4) | ((cx & 8) << 6);
    int ey = (cy & 1) | ((cy & 2) << 2) | ((cy & 4) << 4) | ((cy & 8) << 6);
    int ez = (cz & 1) | ((cz & 2) << 2) | ((cz & 4) << 4) | ((cz & 8) << 6);
    return ex | (ey << 1) | (ez << 2);
}

__device__ __forceinline__ float distf(float4 me, float jx, float jy, float jz, float jw) {
    float dot = fmaf(me.z, jz, fmaf(me.y, jy, me.x * jx));
    return fmaf(-2.f, dot, me.w) + jw;
}

__device__ __forceinline__ float mind2(float4 me, float4 bmin, float4 bmax) {
    float dx = fmaxf(fmaxf(bmin.x - me.x, me.x - bmax.x), 0.f);
    float dy = fmaxf(fmaxf(bmin.y - me.y, me.y - bmax.y), 0.f);
    float dz = fmaxf(fmaxf(bmin.z - me.z, me.z - bmax.z), 0.f);
    return fmaf(dx, dx, fmaf(dy, dy, dz * dz));
}

__device__ __forceinline__ int mbcnt64(unsigned long long m) {
    return __builtin_amdgcn_mbcnt_hi((unsigned int)(m >> 32),
           __builtin_amdgcn_mbcnt_lo((unsigned int)m, 0));
}

__global__ __launch_bounds__(256) void k_prep(
    const float* __restrict__ xyz, const float* __restrict__ W1,
    const float* __restrict__ Wv, const float* __restrict__ Wo,
    float* __restrict__ xyzw, int* __restrict__ hist,
    float* __restrict__ pw1aT, float* __restrict__ pw1bT,
    float* __restrict__ pwvaT, float* __restrict__ pwoT, float* __restrict__ relw,
    float* __restrict__ stats)
{
    int t = threadIdx.x;
    int bid = blockIdx.x;
    if (bid < 128) {
        int pt = bid * 256 + t;
        int b = pt >> 13, n = pt & 8191;
        const float* xb = xyz + (size_t)b * 3 * NN;
        float x = xb[n], y = xb[NN + n], z = xb[2 * NN + n];
        float sq = __fadd_rn(__fadd_rn(__fmul_rn(x, x), __fmul_rn(y, y)), __fmul_rn(z, z));
        ((float4*)xyzw)[pt] = make_float4(x, y, z, sq);
        atomicAdd(&hist[b * NCELL + morton_cell(x, y, z)], 1);
    } else {
        for (int e = t; e < 4096; e += 256) {
            int c = e >> 6, o = e & 63;
            pw1aT[e] = W1[o * 131 + c];
            pw1bT[e] = W1[o * 131 + 64 + c];
            pwvaT[e] = Wv[o * 67 + c];
            pwoT[e]  = Wo[o * 64 + c];
        }
        for (int e = t; e < 384; e += 256) {
            int d = e >> 6, o = e & 63;
            relw[e] = (d < 3) ? W1[o * 131 + 128 + d] : Wv[o * 67 + 64 + (d - 3)];
            stats[e] = 0.0f;
        }
    }
}

// Exclusive scan of per-batch 4096-bin histogram (in place), one block per batch.
__global__ __launch_bounds__(256) void k_scan(int* __restrict__ hist) {
    __shared__ int part[256];
    int b = blockIdx.x, t = threadIdx.x;
    int* h = hist + b * NCELL;
    int loc[16]; int s = 0;
#pragma unroll
    for (int i = 0; i < 16; i++) { loc[i] = h[t * 16 + i]; s += loc[i]; }
    part[t] = s;
    __syncthreads();
    for (int off = 1; off < 256; off <<= 1) {
        int v = (t >= off) ? part[t - off] : 0;
        __syncthreads();
        part[t] += v;
        __syncthreads();
    }
    int run = (t > 0) ? part[t - 1] : 0;
#pragma unroll
    for (int i = 0; i < 16; i++) { int c = loc[i]; h[t * 16 + i] = run; run += c; }
}

__global__ __launch_bounds__(256) void k_scatter(
    const float4* __restrict__ xyzw, int* __restrict__ off,
    float4* __restrict__ sx4, int* __restrict__ sid, int* __restrict__ rank)
{
    int pt = blockIdx.x * 256 + threadIdx.x;
    int b = pt >> 13, n = pt & 8191;
    float4 p = xyzw[pt];
    int cell = morton_cell(p.x, p.y, p.z);
    int dst = atomicAdd(&off[b * NCELL + cell], 1);
    sx4[(b << 13) + dst] = p;
    sid[(b << 13) + dst] = n;
    rank[pt] = dst;
}

// Per-chunk bbox over 64 sorted points. One wave per chunk; 512 chunks total.
__global__ __launch_bounds__(256) void k_bbox(
    const float4* __restrict__ sx4, float4* __restrict__ bbmin, float4* __restrict__ bbmax)
{
    int t = threadIdx.x, lane = t & 63, wl = t >> 6;
    int ch = blockIdx.x * 4 + wl;             // 0..511
    float4 p = sx4[ch * CHSZ + lane];
    float mnx = p.x, mny = p.y, mnz = p.z, mxx = p.x, mxy = p.y, mxz = p.z;
#pragma unroll
    for (int o = 32; o >= 1; o >>= 1) {
        mnx = fminf(mnx, __shfl_xor(mnx, o, 64)); mxx = fmaxf(mxx, __shfl_xor(mxx, o, 64));
        mny = fminf(mny, __shfl_xor(mny, o, 64)); mxy = fmaxf(mxy, __shfl_xor(mxy, o, 64));
        mnz = fminf(mnz, __shfl_xor(mnz, o, 64)); mxz = fmaxf(mxz, __shfl_xor(mxz, o, 64));
    }
    if (lane == 0) {
        bbmin[ch] = make_float4(mnx, mny, mnz, 0.f);
        bbmax[ch] = make_float4(mxx, mxy, mxz, 0.f);
    }
}

// Fused KNN + fp64 refine. TWO waves per 128-thread block, one query per wave
// (16 workgroups/CU x 2 waves = 32 waves/CU -> full occupancy; 1-wave blocks
// capped at 16/CU = 50%). Window sort -> tau = 16th-best (+margin);
// software-pipelined chunk scan appends hits to per-wave LDS via ballot+mbcnt;
// rare overflow -> verified sorted-insert top-32; wave bitonic fp64 refine.
__global__ __launch_bounds__(128) void k_knn(
    const float4* __restrict__ sx4, const int* __restrict__ sid,
    const float4* __restrict__ bbmin, const float4* __restrict__ bbmax,
    int* __restrict__ idx)
{
    __shared__ int cand[2][CAP];
    int lane = threadIdx.x & 63;
    int wl = threadIdx.x >> 6;
    int gq = blockIdx.x * 2 + wl;
    int b = __builtin_amdgcn_readfirstlane(gq >> 13);
    int qs = gq & 8191;
    const float4* sb = sx4 + ((size_t)b << 13);
    const int* ib = sid + ((size_t)b << 13);
    float4 me = sb[qs];                       // wave-uniform
    const float INF = 3.402823466e38f;
    int* wc = cand[wl];

    // phase 1: bitonic-sort the 64-point positional window
    int ws0 = qs - 32; ws0 = ws0 < 0 ? 0 : (ws0 > (NN - 64) ? (NN - 64) : ws0);
    float4 cp = sb[ws0 + lane];
    int cid = ws0 + lane;                     // sorted-space id
    float d = distf(me, cp.x, cp.y, cp.z, cp.w);
#pragma unroll
    for (int k2 = 2; k2 <= 64; k2 <<= 1) {
#pragma unroll
        for (int j2 = k2 >> 1; j2 >= 1; j2 >>= 1) {
            float od = __shfl_xor(d, j2, 64);
            int   oi = __shfl_xor(cid, j2, 64);
            bool up = ((lane & k2) == 0);
            bool lower = ((lane & j2) == 0);
            bool wantMin = (lower == up);
            bool to = wantMin ? (od < d) : (od > d);
            d = to ? od : d; cid = to ? oi : cid;
        }
    }
    // tau from the 16th smallest: superset of fp64 top-16 guaranteed.
    float tau = __int_as_float(__builtin_amdgcn_readlane(__float_as_int(d), 15));
    float tauA = tau * 1.0001f + 1e-5f;

    // chunk masks (evaluated once; reused by fallback with larger tau)
    float md0 = mind2(me, bbmin[b * CHN + lane], bbmax[b * CHN + lane]);
    float md1 = mind2(me, bbmin[b * CHN + 64 + lane], bbmax[b * CHN + 64 + lane]);

    int cnt;
    {
        bool hit = (d <= tauA);
        unsigned long long hm = __ballot(hit);
        if (hit) wc[mbcnt64(hm)] = cid;
        cnt = __popcll(hm);

        unsigned long long bm0 = __ballot(md0 <= tauA);
        unsigned long long bm1 = __ballot(md1 <= tauA);

        // software-pipelined chunk scan (prefetch depth 2)
        int c0 = -1;
        if (bm0)      { c0 = __builtin_ctzll(bm0); bm0 &= bm0 - 1; }
        else if (bm1) { c0 = 64 + __builtin_ctzll(bm1); bm1 &= bm1 - 1; }
        float4 p0 = make_float4(0.f, 0.f, 0.f, 0.f);
        if (c0 >= 0) p0 = sb[c0 * CHSZ + lane];
        while (c0 >= 0) {
            int c1 = -1;
            if (bm0)      { c1 = __builtin_ctzll(bm0); bm0 &= bm0 - 1; }
            else if (bm1) { c1 = 64 + __builtin_ctzll(bm1); bm1 &= bm1 - 1; }
            float4 p1 = p0;
            if (c1 >= 0) p1 = sb[c1 * CHSZ + lane];   // issued before ballots below
            int pos = c0 * CHSZ + lane;
            float dd = distf(me, p0.x, p0.y, p0.z, p0.w);
            bool inwin = (pos >= ws0) && (pos < ws0 + 64);
            bool hit2 = (dd <= tauA) && !inwin;
            unsigned long long m2 = __ballot(hit2);
            if (hit2) {
                int slot = cnt + mbcnt64(m2);
                if (slot < CAP) wc[slot] = pos;
            }
            cnt += __popcll(m2);
            c0 = c1; p0 = p1;
        }
    }

    if (cnt > CAP) {
        // ---- rare fallback: verified sorted-insert top-32 (window-seeded) ----
        bool lt32 = (lane < 32);
        float val = lt32 ? d : INF;
        int vid = cid;
        float tau2 = __int_as_float(__builtin_amdgcn_readlane(__float_as_int(val), 31));
        float t2A = tau2 * 1.0001f + 1e-5f;
        unsigned long long fb0 = __ballot(md0 <= t2A);
        unsigned long long fb1 = __ballot(md1 <= t2A);
        while (fb0 | fb1) {
            int c;
            if (fb0) { c = __builtin_ctzll(fb0); fb0 &= fb0 - 1; }
            else     { c = 64 + __builtin_ctzll(fb1); fb1 &= fb1 - 1; }
            int pos = c * CHSZ + lane;
            float4 p = sb[pos];
            float dd = distf(me, p.x, p.y, p.z, p.w);
            bool inwin = (pos >= ws0) && (pos < ws0 + 64);
            dd = inwin ? INF : dd;
            unsigned long long m = __ballot(dd < tau2);
            while (m) {
                int hl = __builtin_ctzll(m); m &= m - 1;
                float dn = __int_as_float(
                    __builtin_amdgcn_readlane(__float_as_int(dd), hl));
                int jn = c * CHSZ + hl;
                unsigned long long bl = __ballot(val < dn);
                int pos2 = __popcll(bl);
                float sv = __shfl_up(val, 1, 64);
                int   sj = __shfl_up(vid, 1, 64);
                float nv = (lane > pos2) ? sv : val; nv = (lane == pos2) ? dn : nv;
                int   nj = (lane > pos2) ? sj : vid; nj = (lane == pos2) ? jn : nj;
                val = lt32 ? nv : val;
                vid = lt32 ? nj : vid;
                tau2 = __int_as_float(__builtin_amdgcn_readlane(__float_as_int(val), 31));
            }
        }
        if (lt32) wc[lane] = vid;
        cnt = 32;
    }

    // ---- merged fp64 refine: lane c = candidate c; bitonic (dd, oj) ----
    double mx = (double)me.x, my = (double)me.y, mz = (double)me.z;
    double msq = (mx * mx + my * my) + mz * mz;
    int j = 0, oj = 0x40000000 + lane;        // unique sentinel > any valid oj
    double dd = 1e300;
    if (lane < cnt) {
        j = wc[lane];
        float4 cj = sb[j];
        oj = ib[j];
        double jx = (double)cj.x, jy = (double)cj.y, jz = (double)cj.z;
        double dot = (mx * jx + my * jy) + mz * jz;
        double sqj = (jx * jx + jy * jy) + jz * jz;
        dd = (-2.0 * dot + msq) + sqj;
    }
#pragma unroll
    for (int k2 = 2; k2 <= 64; k2 <<= 1) {
#pragma unroll
        for (int j2 = k2 >> 1; j2 >= 1; j2 >>= 1) {
            double od = __shfl_xor(dd, j2, 64);
            int   ooj = __shfl_xor(oj, j2, 64);
            int   oid = __shfl_xor(j, j2, 64);
            bool up = ((lane & k2) == 0);
            bool lower = ((lane & j2) == 0);
            bool wantMin = (lower == up);
            bool oless = (od < dd) || (od == dd && ooj < oj);
            bool take = wantMin ? oless : !oless;
            dd = take ? od : dd; oj = take ? ooj : oj; j = take ? oid : j;
        }
    }
    if (lane < 16) idx[(size_t)gq * 16 + lane] = j;
}

// Per-point GEMVs, output scattered to SORTED layout via rank.
__global__ __launch_bounds__(256) void k_F(
    const float* __restrict__ feats, const float* __restrict__ b1, const float* __restrict__ bv,
    const float* __restrict__ pw1aT, const float* __restrict__ pw1bT, const float* __restrict__ pwvaT,
    const int* __restrict__ rank,
    float* __restrict__ F1, float* __restrict__ F2, float* __restrict__ FV)
{
    int t = threadIdx.x;
    int lane = t & 63;
    int wave = t >> 6;
    int pt0 = blockIdx.x * 64 + wave * 16;
    int b   = __builtin_amdgcn_readfirstlane(pt0 >> 13);
    int n0  = __builtin_amdgcn_readfirstlane(pt0 & 8191);
    const float* fb = feats + (size_t)b * CC * NN;
    float accA[16], accB[16], accV[16];
    float bb1 = b1[lane], bbv = bv[lane];
#pragma unroll
    for (int p = 0; p < 16; p++) { accA[p] = bb1; accB[p] = 0.f; accV[p] = bbv; }
    for (int c = 0; c < 64; c++) {
        float wA = pw1aT[c * 64 + lane];
        float wB = pw1bT[c * 64 + lane];
        float wV = pwvaT[c * 64 + lane];
        const float* fr = fb + (size_t)c * NN + n0;
#pragma unroll
        for (int p = 0; p < 16; p++) {
            float f = fr[p];
            accA[p] = fmaf(wA, f, accA[p]);
            accB[p] = fmaf(wB, f, accB[p]);
            accV[p] = fmaf(wV, f, accV[p]);
        }
    }
#pragma unroll
    for (int p = 0; p < 16; p++) {
        int dst = (b << 13) + rank[pt0 + p];     // wave-uniform scalar
        F1[(size_t)dst * 64 + lane] = accA[p];
        F2[(size_t)dst * 64 + lane] = accB[p];
        FV[(size_t)dst * 64 + lane] = accV[p];
    }
}

// BN stats pass. XCD-swizzled; block partials to PH (NO contended atomics).
__global__ __launch_bounds__(256) void k_hv(
    const float4* __restrict__ sx4, const int* __restrict__ idx,
    const float* __restrict__ F1, const float* __restrict__ F2, const float* __restrict__ FV,
    const float* __restrict__ relw, float* __restrict__ ph)
{
    __shared__ float red[4][4][64];
    int t = threadIdx.x;
    int lane = t & 63;
    int wl = t >> 6;
    int bx = blockIdx.x;                       // 2048 blocks
    int vb = (bx & 7) * 256 + (bx >> 3);       // XCD-aware swizzle
    float rw0 = relw[0 * 64 + lane], rw1 = relw[1 * 64 + lane], rw2 = relw[2 * 64 + lane];
    float rw3 = relw[3 * 64 + lane], rw4 = relw[4 * 64 + lane], rw5 = relw[5 * 64 + lane];
    float sh = 0.f, sh2 = 0.f, sv = 0.f, sv2 = 0.f;
    for (int i = 0; i < 4; i++) {
        int gq = __builtin_amdgcn_readfirstlane(vb * 16 + wl * 4 + i);  // contiguous
        int b = gq >> 13;
        const float4* sb = sx4 + ((size_t)b << 13);
        float4 me = sb[gq & 8191];
        float F1v = F1[(size_t)gq * 64 + lane];
        const int* ip = idx + (size_t)gq * 16;
#pragma unroll
        for (int kb = 0; kb < 2; kb++) {
            float4 cjA[8]; float f2A[8], fvA[8];
#pragma unroll
            for (int j = 0; j < 8; j++) {
                int gl = ip[kb * 8 + j];
                cjA[j] = sb[gl];
                size_t go = (size_t)((b << 13) + gl) * 64 + lane;
                f2A[j] = F2[go];
                fvA[j] = FV[go];
            }
#pragma unroll
            for (int j = 0; j < 8; j++) {
                float rx = cjA[j].x - me.x, ry = cjA[j].y - me.y, rz = cjA[j].z - me.z;
                float h = F1v + f2A[j];
                h = fmaf(rw0, rx, h); h = fmaf(rw1, ry, h); h = fmaf(rw2, rz, h);
                float v = fvA[j];
                v = fmaf(rw3, rx, v); v = fmaf(rw4, ry, v); v = fmaf(rw5, rz, v);
                sh += h; sh2 = fmaf(h, h, sh2);
                sv += v; sv2 = fmaf(v, v, sv2);
            }
        }
    }
    red[0][wl][lane] = sh; red[1][wl][lane] = sh2;
    red[2][wl][lane] = sv; red[3][wl][lane] = sv2;
    __syncthreads();
    float s = red[wl][0][lane] + red[wl][1][lane] + red[wl][2][lane] + red[wl][3][lane];
    ph[(size_t)bx * 256 + wl * 64 + lane] = s;     // plain store, no contention
}

// Reduce PH -> stats[0..255]. 32 blocks x 64 rows each; light atomics (32/addr).
__global__ __launch_bounds__(256) void k_red1(
    const float* __restrict__ ph, float* __restrict__ stats)
{
    int t = threadIdx.x, p = blockIdx.x;
    float acc = 0.f;
    for (int i = 0; i < 64; i++)
        acc += ph[(size_t)(p * 64 + i) * 256 + t];
    atomicAdd(&stats[t], acc);
}

// Attention in SORTED space, XCD-swizzled. Barrier-free, atomic-free, LDS-free.
__global__ __launch_bounds__(256) void k_attn(
    const float4* __restrict__ sx4,
    const int* __restrict__ idx,
    const float* __restrict__ F1, const float* __restrict__ F2, const float* __restrict__ FV,
    const float* __restrict__ relw, const float* __restrict__ stats,
    const float* __restrict__ g1, const float* __restrict__ be1,
    const float* __restrict__ W2, const float* __restrict__ b2,
    const float* __restrict__ gv, const float* __restrict__ bev,
    float* __restrict__ outv)
{
    int t = threadIdx.x;
    int lane = t & 63;
    int wl = t >> 6;
    int bx = blockIdx.x;                      // 8192 blocks
    int vb = (bx & 7) * 1024 + (bx >> 3);     // XCD-aware swizzle
    int gq = vb * 4 + wl;                     // sorted-global query
    const float invM = 1.f / 524288.f;
    float hm = stats[lane] * invM, hq = stats[64 + lane] * invM;
    float s1 = g1[lane] * rsqrtf(hq - hm * hm + EPSBN);
    float t1 = be1[lane] - s1 * hm;
    float vm = stats[128 + lane] * invM, vq = stats[192 + lane] * invM;
    float sv = gv[lane] * rsqrtf(vq - vm * vm + EPSBN);
    float tv = bev[lane] - sv * vm;
    float rw0 = relw[0 * 64 + lane], rw1 = relw[1 * 64 + lane], rw2 = relw[2 * 64 + lane];
    float rw3 = relw[3 * 64 + lane], rw4 = relw[4 * 64 + lane], rw5 = relw[5 * 64 + lane];
    float w2v = W2[lane];
    float b2v = b2[0];

    int b = __builtin_amdgcn_readfirstlane(gq >> 13);
    const float4* sb = sx4 + ((size_t)b << 13);
    float4 me = sb[gq & 8191];
    float F1v = F1[(size_t)gq * 64 + lane];
    const int* ip = idx + (size_t)gq * 16;
    float ek[16], vk[16];
#pragma unroll
    for (int kb = 0; kb < 2; kb++) {
        float4 cjA[8]; float f2A[8], fvA[8];
#pragma unroll
        for (int j = 0; j < 8; j++) {
            int gl = ip[kb * 8 + j];
            cjA[j] = sb[gl];
            size_t go = (size_t)((b << 13) + gl) * 64 + lane;
            f2A[j] = F2[go];
            fvA[j] = FV[go];
        }
#pragma unroll
        for (int j = 0; j < 8; j++) {
            int k = kb * 8 + j;
            float rx = cjA[j].x - me.x, ry = cjA[j].y - me.y, rz = cjA[j].z - me.z;
            float h = F1v + f2A[j];
            h = fmaf(rw0, rx, h); h = fmaf(rw1, ry, h); h = fmaf(rw2, rz, h);
            float a = fmaxf(fmaf(s1, h, t1), 0.f);
            float v = fvA[j];
            v = fmaf(rw3, rx, v); v = fmaf(rw4, ry, v); v = fmaf(rw5, rz, v);
            vk[k] = fmaxf(fmaf(sv, v, tv), 0.f);
            float lg = w2v * a;
#pragma unroll
            for (int off = 32; off >= 1; off >>= 1) lg += __shfl_xor(lg, off, 64);
            ek[k] = lg + b2v;
        }
    }
    float mx = ek[0];
#pragma unroll
    for (int k = 1; k < 16; k++) mx = fmaxf(mx, ek[k]);
    float ssum = 0.f;
#pragma unroll
    for (int k = 0; k < 16; k++) { float e = __expf(ek[k] - mx); ek[k] = e; ssum += e; }
    float acc = 0.f;
#pragma unroll
    for (int k = 0; k < 16; k++) acc = fmaf(ek[k], vk[k], acc);
    outv[(size_t)gq * 64 + lane] = acc / ssum;
}

// Wo matvec + o-stats: out rows (sorted) -> o_pre rows (ORIGINAL layout) + PO partials.
__global__ __launch_bounds__(256) void k_o(
    const float* __restrict__ outv, const float* __restrict__ pwoT,
    const float* __restrict__ bo, const int* __restrict__ sid,
    float* __restrict__ opre, float* __restrict__ po)
{
    __shared__ float red[2][4][64];
    int t = threadIdx.x;
    int lane = t & 63;
    int wl = t >> 6;
    int gq0 = blockIdx.x * 64 + wl * 16;       // 16 sorted points per wave
    int b = __builtin_amdgcn_readfirstlane(gq0 >> 13);
    float acc[16];
    float bov = bo[lane];
#pragma unroll
    for (int p = 0; p < 16; p++) acc[p] = bov;
    for (int c = 0; c < 64; c++) {
        float w = pwoT[c * 64 + lane];
        const float* orow = outv + (size_t)gq0 * 64 + c;
#pragma unroll
        for (int p = 0; p < 16; p++)
            acc[p] = fmaf(w, orow[p * 64], acc[p]);
    }
    float so = 0.f, so2 = 0.f;
#pragma unroll
    for (int p = 0; p < 16; p++) {
        int orig = (b << 13) + sid[gq0 + p];   // wave-uniform scalar
        opre[(size_t)orig * 64 + lane] = acc[p];
        so += acc[p]; so2 = fmaf(acc[p], acc[p], so2);
    }
    red[0][wl][lane] = so; red[1][wl][lane] = so2;
    __syncthreads();
    if (wl < 2) {
        float s = red[wl][0][lane] + red[wl][1][lane] + red[wl][2][lane] + red[wl][3][lane];
        po[(size_t)blockIdx.x * 128 + wl * 64 + lane] = s;
    }
}

// Reduce PO -> stats[256..383]. 8 blocks x 64 rows; light atomics.
__global__ __launch_bounds__(256) void k_red2(
    const float* __restrict__ po, float* __restrict__ stats)
{
    int t = threadIdx.x, p = blockIdx.x;
    if (t < 128) {
        float acc = 0.f;
        for (int i = 0; i < 64; i++)
            acc += po[(size_t)(p * 64 + i) * 128 + t];
        atomicAdd(&stats[256 + t], acc);
    }
}

// Final: BN(o)+relu + residual feats, transpose [B,N,C]->[B,C,N]
__global__ __launch_bounds__(256) void k_final(
    const float* __restrict__ opre, const float* __restrict__ stats,
    const float* __restrict__ go, const float* __restrict__ beo,
    const float* __restrict__ feats, float* __restrict__ out)
{
    __shared__ float tile[64][65];
    int t = threadIdx.x;
    int blk = blockIdx.x;
    int b = blk >> 7, n0 = (blk & 127) << 6;
#pragma unroll
    for (int i = 0; i < 16; i++) {
        int e = t + i * 256;
        int r = e >> 6, c = e & 63;
        tile[r][c] = opre[((size_t)((b << 13) + n0 + r)) * 64 + c];
    }
    __syncthreads();
    const float invM = 1.f / 32768.f;
    int lane = t & 63, wv = t >> 6;
#pragma unroll
    for (int i = 0; i < 16; i++) {
        int c = wv * 16 + i;
        float om = stats[256 + c] * invM, oq = stats[320 + c] * invM;
        float so = go[c] * rsqrtf(oq - om * om + EPSBN);
        float to = beo[c] - so * om;
        float val = fmaxf(fmaf(so, tile[lane][c], to), 0.f);
        size_t oix = ((size_t)b * 64 + c) * NN + n0 + lane;
        out[oix] = val + feats[oix];
    }
}

extern "C" void kernel_launch(void* const* d_in, const int* in_sizes, int n_in,
                              void* d_out, int out_size, void* d_ws, size_t ws_size,
                              hipStream_t stream)
{
    const float* xyz  = (const float*)d_in[0];
    const float* feats= (const float*)d_in[1];
    const float* W1   = (const float*)d_in[2];
    const float* b1   = (const float*)d_in[3];
    const float* g1   = (const float*)d_in[4];
    const float* be1  = (const float*)d_in[5];
    const float* W2   = (const float*)d_in[6];
    const float* b2   = (const float*)d_in[7];
    const float* Wv   = (const float*)d_in[8];
    const float* bv   = (const float*)d_in[9];
    const float* gv   = (const float*)d_in[10];
    const float* bev  = (const float*)d_in[11];
    const float* Wo   = (const float*)d_in[12];
    const float* bo   = (const float*)d_in[13];
    const float* go   = (const float*)d_in[14];
    const float* beo  = (const float*)d_in[15];

    float* ws = (float*)d_ws;
    float* xyzw  = ws + OFF_XYZW;
    float* pw1aT = ws + OFF_PW1AT;
    float* pw1bT = ws + OFF_PW1BT;
    float* pwvaT = ws + OFF_PWVAT;
    float* pwoT  = ws + OFF_PWOT;
    float* relw  = ws + OFF_RELW;
    float* stats = ws + OFF_STATS;
    int*   idx   = (int*)(ws + OFF_IDX);
    float* outv  = ws + OFF_OUTV;
    float4* sx4  = (float4*)(ws + OFF_SX4);
    int*   sid   = (int*)(ws + OFF_SID);
    int*   hist  = (int*)(ws + OFF_HIST);
    float4* bbmn = (float4*)(ws + OFF_BB);
    float4* bbmx = (float4*)(ws + OFF_BB + 2048);
    int*   rank  = (int*)(ws + OFF_RANK);
    float* ph    = ws + OFF_PH;
    float* po    = ws + OFF_PO;
    float* F1    = ws + OFF_F1;
    float* F2    = ws + OFF_F2;
    float* FV    = ws + OFF_FV;
    float* opre  = ws + OFF_OPRE;   // aliases F1 (dead after k_attn)

    hipMemsetAsync(hist, 0, BB * NCELL * sizeof(int), stream);
    k_prep<<<129, 256, 0, stream>>>(xyz, W1, Wv, Wo, xyzw, hist,
                                    pw1aT, pw1bT, pwvaT, pwoT, relw, stats);
    k_scan<<<4, 256, 0, stream>>>(hist);
    k_scatter<<<128, 256, 0, stream>>>((const float4*)xyzw, hist, sx4, sid, rank);
    k_bbox<<<128, 256, 0, stream>>>((const float4*)sx4, bbmn, bbmx);
    k_F<<<512, 256, 0, stream>>>(feats, b1, bv, pw1aT, pw1bT, pwvaT, rank, F1, F2, FV);
    k_knn<<<NPTS / 2, 128, 0, stream>>>((const float4*)sx4, sid, bbmn, bbmx, idx);
    k_hv<<<2048, 256, 0, stream>>>((const float4*)sx4, idx, F1, F2, FV, relw, ph);
    k_red1<<<32, 256, 0, stream>>>(ph, stats);
    k_attn<<<8192, 256, 0, stream>>>((const float4*)sx4, idx, F1, F2, FV, relw, stats,
                                     g1, be1, W2, b2, gv, bev, outv);
    k_o<<<512, 256, 0, stream>>>(outv, pwoT, bo, sid, opre, po);
    k_red2<<<8, 256, 0, stream>>>(po, stats);
    k_final<<<512, 256, 0, stream>>>(opre, stats, go, beo, feats, (float*)d_out);
}

// Round 15
// 313.706 us; speedup vs baseline: 1.4231x; 1.0130x over previous
//
#include <hip/hip_runtime.h>
#include <math.h>

// Problem constants
#define BB 4
#define NN 8192
#define CC 64
#define KK 16
#define HH 64
#define NPTS (BB*NN)   // 32768
#define EPSBN 1e-5f
#define CAP 64         // candidate buffer per query (fp64 refine picks 16)
#define NCELL 4096     // 16^3 Morton cells
#define CHN 128        // chunks per batch
#define CHSZ 64        // points per chunk

// ---------------- ws layout (float offsets) ----------------
#define OFF_XYZW  0
#define OFF_PW1AT 131072
#define OFF_PW1BT 135168
#define OFF_PWVAT 139264
#define OFF_PWOT  143360
#define OFF_RELW  147456
#define OFF_STATS 147840
#define OFF_IDX   148224      // idx: 32768*16 ints (SORTED-space neighbor ids)
#define OFF_OPRE  672512      // [32768][64] o_pre, ORIGINAL layout (old OUTV region)
#define OFF_SX4   2769664     // sorted xyzw [4][8192] float4
#define OFF_SID   2900736     // sorted->orig ids [4][8192] int
#define OFF_HIST  2933504     // [4][4096] int
#define OFF_RANK  2950912     // orig->sorted rank [4][8192] int
#define OFF_PH    2983680     // PH2 [256][256] h/v-stat buckets
#define OFF_PO    3049216     // PO2 [256][128] o-stat buckets
#define OFF_BB    3606272     // bbmin[512] f4 (2048) + bbmax[512] f4 (2048)
#define OFF_F1    4866816     // SORTED layout
#define OFF_F2    6963968     // SORTED layout
#define OFF_FV    9061120     // SORTED layout

__device__ __forceinline__ int morton_cell(float x, float y, float z) {
    int cx = (int)floorf((x + 4.f) * 2.f);
    int cy = (int)floorf((y + 4.f) * 2.f);
    int cz = (int)floorf((z + 4.f) * 2.f);
    cx = cx < 0 ? 0 : (cx > 15 ? 15 : cx);
    cy = cy < 0 ? 0 : (cy > 15 ? 15 : cy);
    cz = cz < 0 ? 0 : (cz > 15 ? 15 : cz);
    int ex = (cx & 1) | ((cx & 2) << 2) | ((cx & 4) << 4) | ((cx & 8) << 6);
    int ey = (cy & 1) | ((cy & 2) << 2) | ((cy & 4) << 4) | ((cy & 8) << 6);
    int ez = (cz & 1) | ((cz & 2) << 2) | ((cz & 4) << 4) | ((cz & 8) << 6);
    return ex | (ey << 1) | (ez << 2);
}

__device__ __forceinline__ float distf(float4 me, float jx, float jy, float jz, float jw) {
    float dot = fmaf(me.z, jz, fmaf(me.y, jy, me.x * jx));
    return fmaf(-2.f, dot, me.w) + jw;
}

__device__ __forceinline__ float mind2(float4 me, float4 bmin, float4 bmax) {
    float dx = fmaxf(fmaxf(bmin.x - me.x, me.x - bmax.x), 0.f);
    float dy = fmaxf(fmaxf(bmin.y - me.y, me.y - bmax.y), 0.f);
    float dz = fmaxf(fmaxf(bmin.z - me.z, me.z - bmax.z), 0.f);
    return fmaf(dx, dx, fmaf(dy, dy, dz * dz));
}

__device__ __forceinline__ int mbcnt64(unsigned long long m) {
    return __builtin_amdgcn_mbcnt_hi((unsigned int)(m >> 32),
           __builtin_amdgcn_mbcnt_lo((unsigned int)m, 0));
}

__global__ __launch_bounds__(256) void k_prep(
    const float* __restrict__ xyz, const float* __restrict__ W1,
    const float* __restrict__ Wv, const float* __restrict__ Wo,
    float* __restrict__ xyzw, int* __restrict__ hist,
    float* __restrict__ pw1aT, float* __restrict__ pw1bT,
    float* __restrict__ pwvaT, float* __restrict__ pwoT, float* __restrict__ relw,
    float* __restrict__ stats)
{
    int t = threadIdx.x;
    int bid = blockIdx.x;
    if (bid < 128) {
        int pt = bid * 256 + t;
        int b = pt >> 13, n = pt & 8191;
        const float* xb = xyz + (size_t)b * 3 * NN;
        float x = xb[n], y = xb[NN + n], z = xb[2 * NN + n];
        float sq = __fadd_rn(__fadd_rn(__fmul_rn(x, x), __fmul_rn(y, y)), __fmul_rn(z, z));
        ((float4*)xyzw)[pt] = make_float4(x, y, z, sq);
        atomicAdd(&hist[b * NCELL + morton_cell(x, y, z)], 1);
    } else {
        for (int e = t; e < 4096; e += 256) {
            int c = e >> 6, o = e & 63;
            pw1aT[e] = W1[o * 131 + c];
            pw1bT[e] = W1[o * 131 + 64 + c];
            pwvaT[e] = Wv[o * 67 + c];
            pwoT[e]  = Wo[o * 64 + c];
        }
        for (int e = t; e < 384; e += 256) {
            int d = e >> 6, o = e & 63;
            relw[e] = (d < 3) ? W1[o * 131 + 128 + d] : Wv[o * 67 + 64 + (d - 3)];
            stats[e] = 0.0f;
        }
    }
}

// Exclusive scan of per-batch 4096-bin histogram (in place), one block per batch.
__global__ __launch_bounds__(256) void k_scan(int* __restrict__ hist) {
    __shared__ int part[256];
    int b = blockIdx.x, t = threadIdx.x;
    int* h = hist + b * NCELL;
    int loc[16]; int s = 0;
#pragma unroll
    for (int i = 0; i < 16; i++) { loc[i] = h[t * 16 + i]; s += loc[i]; }
    part[t] = s;
    __syncthreads();
    for (int off = 1; off < 256; off <<= 1) {
        int v = (t >= off) ? part[t - off] : 0;
        __syncthreads();
        part[t] += v;
        __syncthreads();
    }
    int run = (t > 0) ? part[t - 1] : 0;
#pragma unroll
    for (int i = 0; i < 16; i++) { int c = loc[i]; h[t * 16 + i] = run; run += c; }
}

__global__ __launch_bounds__(256) void k_scatter(
    const float4* __restrict__ xyzw, int* __restrict__ off,
    float4* __restrict__ sx4, int* __restrict__ sid, int* __restrict__ rank)
{
    int pt = blockIdx.x * 256 + threadIdx.x;
    int b = pt >> 13, n = pt & 8191;
    float4 p = xyzw[pt];
    int cell = morton_cell(p.x, p.y, p.z);
    int dst = atomicAdd(&off[b * NCELL + cell], 1);
    sx4[(b << 13) + dst] = p;
    sid[(b << 13) + dst] = n;
    rank[pt] = dst;
}

// Per-chunk bbox over 64 sorted points. One wave per chunk; 512 chunks total.
__global__ __launch_bounds__(256) void k_bbox(
    const float4* __restrict__ sx4, float4* __restrict__ bbmin, float4* __restrict__ bbmax)
{
    int t = threadIdx.x, lane = t & 63, wl = t >> 6;
    int ch = blockIdx.x * 4 + wl;             // 0..511
    float4 p = sx4[ch * CHSZ + lane];
    float mnx = p.x, mny = p.y, mnz = p.z, mxx = p.x, mxy = p.y, mxz = p.z;
#pragma unroll
    for (int o = 32; o >= 1; o >>= 1) {
        mnx = fminf(mnx, __shfl_xor(mnx, o, 64)); mxx = fmaxf(mxx, __shfl_xor(mxx, o, 64));
        mny = fminf(mny, __shfl_xor(mny, o, 64)); mxy = fmaxf(mxy, __shfl_xor(mxy, o, 64));
        mnz = fminf(mnz, __shfl_xor(mnz, o, 64)); mxz = fmaxf(mxz, __shfl_xor(mxz, o, 64));
    }
    if (lane == 0) {
        bbmin[ch] = make_float4(mnx, mny, mnz, 0.f);
        bbmax[ch] = make_float4(mxx, mxy, mxz, 0.f);
    }
}

// Per-point GEMVs, output scattered to SORTED layout via rank.
__global__ __launch_bounds__(256) void k_F(
    const float* __restrict__ feats, const float* __restrict__ b1, const float* __restrict__ bv,
    const float* __restrict__ pw1aT, const float* __restrict__ pw1bT, const float* __restrict__ pwvaT,
    const int* __restrict__ rank,
    float* __restrict__ F1, float* __restrict__ F2, float* __restrict__ FV)
{
    int t = threadIdx.x;
    int lane = t & 63;
    int wave = t >> 6;
    int pt0 = blockIdx.x * 64 + wave * 16;
    int b   = __builtin_amdgcn_readfirstlane(pt0 >> 13);
    int n0  = __builtin_amdgcn_readfirstlane(pt0 & 8191);
    const float* fb = feats + (size_t)b * CC * NN;
    float accA[16], accB[16], accV[16];
    float bb1 = b1[lane], bbv = bv[lane];
#pragma unroll
    for (int p = 0; p < 16; p++) { accA[p] = bb1; accB[p] = 0.f; accV[p] = bbv; }
    for (int c = 0; c < 64; c++) {
        float wA = pw1aT[c * 64 + lane];
        float wB = pw1bT[c * 64 + lane];
        float wV = pwvaT[c * 64 + lane];
        const float* fr = fb + (size_t)c * NN + n0;
#pragma unroll
        for (int p = 0; p < 16; p++) {
            float f = fr[p];
            accA[p] = fmaf(wA, f, accA[p]);
            accB[p] = fmaf(wB, f, accB[p]);
            accV[p] = fmaf(wV, f, accV[p]);
        }
    }
#pragma unroll
    for (int p = 0; p < 16; p++) {
        int dst = (b << 13) + rank[pt0 + p];     // wave-uniform scalar
        F1[(size_t)dst * 64 + lane] = accA[p];
        F2[(size_t)dst * 64 + lane] = accB[p];
        FV[(size_t)dst * 64 + lane] = accV[p];
    }
}

// Fused KNN + fp64 refine + h/v BN-stats. TWO waves per 128-thread block, one
// query per wave. Window sort -> tau16; pipelined chunk scan -> LDS candidates;
// rare overflow -> verified sorted-insert; wave bitonic fp64 refine -> idx;
// then the wave ALREADY holds the 16 neighbor ids in registers: gather
// F2/FV rows and accumulate h/v sum/sumsq into PH2 buckets (128 RMW/addr).
__global__ __launch_bounds__(128) void k_knn(
    const float4* __restrict__ sx4, const int* __restrict__ sid,
    const float4* __restrict__ bbmin, const float4* __restrict__ bbmax,
    const float* __restrict__ F1, const float* __restrict__ F2, const float* __restrict__ FV,
    const float* __restrict__ relw,
    int* __restrict__ idx, float* __restrict__ ph2)
{
    __shared__ int cand[2][CAP];
    int lane = threadIdx.x & 63;
    int wl = threadIdx.x >> 6;
    int gq = blockIdx.x * 2 + wl;
    int b = __builtin_amdgcn_readfirstlane(gq >> 13);
    int qs = gq & 8191;
    const float4* sb = sx4 + ((size_t)b << 13);
    const int* ib = sid + ((size_t)b << 13);
    float4 me = sb[qs];                       // wave-uniform
    const float INF = 3.402823466e38f;
    int* wc = cand[wl];

    // phase 1: bitonic-sort the 64-point positional window
    int ws0 = qs - 32; ws0 = ws0 < 0 ? 0 : (ws0 > (NN - 64) ? (NN - 64) : ws0);
    float4 cp = sb[ws0 + lane];
    int cid = ws0 + lane;                     // sorted-space id
    float d = distf(me, cp.x, cp.y, cp.z, cp.w);
#pragma unroll
    for (int k2 = 2; k2 <= 64; k2 <<= 1) {
#pragma unroll
        for (int j2 = k2 >> 1; j2 >= 1; j2 >>= 1) {
            float od = __shfl_xor(d, j2, 64);
            int   oi = __shfl_xor(cid, j2, 64);
            bool up = ((lane & k2) == 0);
            bool lower = ((lane & j2) == 0);
            bool wantMin = (lower == up);
            bool to = wantMin ? (od < d) : (od > d);
            d = to ? od : d; cid = to ? oi : cid;
        }
    }
    float tau = __int_as_float(__builtin_amdgcn_readlane(__float_as_int(d), 15));
    float tauA = tau * 1.0001f + 1e-5f;

    float md0 = mind2(me, bbmin[b * CHN + lane], bbmax[b * CHN + lane]);
    float md1 = mind2(me, bbmin[b * CHN + 64 + lane], bbmax[b * CHN + 64 + lane]);

    int cnt;
    {
        bool hit = (d <= tauA);
        unsigned long long hm = __ballot(hit);
        if (hit) wc[mbcnt64(hm)] = cid;
        cnt = __popcll(hm);

        unsigned long long bm0 = __ballot(md0 <= tauA);
        unsigned long long bm1 = __ballot(md1 <= tauA);

        int c0 = -1;
        if (bm0)      { c0 = __builtin_ctzll(bm0); bm0 &= bm0 - 1; }
        else if (bm1) { c0 = 64 + __builtin_ctzll(bm1); bm1 &= bm1 - 1; }
        float4 p0 = make_float4(0.f, 0.f, 0.f, 0.f);
        if (c0 >= 0) p0 = sb[c0 * CHSZ + lane];
        while (c0 >= 0) {
            int c1 = -1;
            if (bm0)      { c1 = __builtin_ctzll(bm0); bm0 &= bm0 - 1; }
            else if (bm1) { c1 = 64 + __builtin_ctzll(bm1); bm1 &= bm1 - 1; }
            float4 p1 = p0;
            if (c1 >= 0) p1 = sb[c1 * CHSZ + lane];
            int pos = c0 * CHSZ + lane;
            float dd = distf(me, p0.x, p0.y, p0.z, p0.w);
            bool inwin = (pos >= ws0) && (pos < ws0 + 64);
            bool hit2 = (dd <= tauA) && !inwin;
            unsigned long long m2 = __ballot(hit2);
            if (hit2) {
                int slot = cnt + mbcnt64(m2);
                if (slot < CAP) wc[slot] = pos;
            }
            cnt += __popcll(m2);
            c0 = c1; p0 = p1;
        }
    }

    if (cnt > CAP) {
        // rare fallback: verified sorted-insert top-32 (window-seeded)
        bool lt32 = (lane < 32);
        float val = lt32 ? d : INF;
        int vid = cid;
        float tau2 = __int_as_float(__builtin_amdgcn_readlane(__float_as_int(val), 31));
        float t2A = tau2 * 1.0001f + 1e-5f;
        unsigned long long fb0 = __ballot(md0 <= t2A);
        unsigned long long fb1 = __ballot(md1 <= t2A);
        while (fb0 | fb1) {
            int c;
            if (fb0) { c = __builtin_ctzll(fb0); fb0 &= fb0 - 1; }
            else     { c = 64 + __builtin_ctzll(fb1); fb1 &= fb1 - 1; }
            int pos = c * CHSZ + lane;
            float4 p = sb[pos];
            float dd = distf(me, p.x, p.y, p.z, p.w);
            bool inwin = (pos >= ws0) && (pos < ws0 + 64);
            dd = inwin ? INF : dd;
            unsigned long long m = __ballot(dd < tau2);
            while (m) {
                int hl = __builtin_ctzll(m); m &= m - 1;
                float dn = __int_as_float(
                    __builtin_amdgcn_readlane(__float_as_int(dd), hl));
                int jn = c * CHSZ + hl;
                unsigned long long bl = __ballot(val < dn);
                int pos2 = __popcll(bl);
                float sv = __shfl_up(val, 1, 64);
                int   sj = __shfl_up(vid, 1, 64);
                float nv = (lane > pos2) ? sv : val; nv = (lane == pos2) ? dn : nv;
                int   nj = (lane > pos2) ? sj : vid; nj = (lane == pos2) ? jn : nj;
                val = lt32 ? nv : val;
                vid = lt32 ? nj : vid;
                tau2 = __int_as_float(__builtin_amdgcn_readlane(__float_as_int(val), 31));
            }
        }
        if (lt32) wc[lane] = vid;
        cnt = 32;
    }

    // merged fp64 refine: lane c = candidate c; bitonic (dd, oj)
    double mx = (double)me.x, my = (double)me.y, mz = (double)me.z;
    double msq = (mx * mx + my * my) + mz * mz;
    int j = 0, oj = 0x40000000 + lane;        // unique sentinel > any valid oj
    double dd = 1e300;
    if (lane < cnt) {
        j = wc[lane];
        float4 cj = sb[j];
        oj = ib[j];
        double jx = (double)cj.x, jy = (double)cj.y, jz = (double)cj.z;
        double dot = (mx * jx + my * jy) + mz * jz;
        double sqj = (jx * jx + jy * jy) + jz * jz;
        dd = (-2.0 * dot + msq) + sqj;
    }
#pragma unroll
    for (int k2 = 2; k2 <= 64; k2 <<= 1) {
#pragma unroll
        for (int j2 = k2 >> 1; j2 >= 1; j2 >>= 1) {
            double od = __shfl_xor(dd, j2, 64);
            int   ooj = __shfl_xor(oj, j2, 64);
            int   oid = __shfl_xor(j, j2, 64);
            bool up = ((lane & k2) == 0);
            bool lower = ((lane & j2) == 0);
            bool wantMin = (lower == up);
            bool oless = (od < dd) || (od == dd && ooj < oj);
            bool take = wantMin ? oless : !oless;
            dd = take ? od : dd; oj = take ? ooj : oj; j = take ? oid : j;
        }
    }
    if (lane < 16) idx[(size_t)gq * 16 + lane] = j;

    // ---- fused h/v BN stats for this query's 16 neighbors ----
    float rw0 = relw[0 * 64 + lane], rw1 = relw[1 * 64 + lane], rw2 = relw[2 * 64 + lane];
    float rw3 = relw[3 * 64 + lane], rw4 = relw[4 * 64 + lane], rw5 = relw[5 * 64 + lane];
    float F1v = F1[(size_t)gq * 64 + lane];
    float sh = 0.f, sh2 = 0.f, sv = 0.f, sv2 = 0.f;
#pragma unroll
    for (int kb = 0; kb < 2; kb++) {
        float4 cjA[8]; float f2A[8], fvA[8];
#pragma unroll
        for (int jj = 0; jj < 8; jj++) {
            int g = __builtin_amdgcn_readlane(j, kb * 8 + jj);   // k-th neighbor id
            cjA[jj] = sb[g];
            size_t go = (size_t)((b << 13) + g) * 64 + lane;
            f2A[jj] = F2[go];
            fvA[jj] = FV[go];
        }
#pragma unroll
        for (int jj = 0; jj < 8; jj++) {
            float rx = cjA[jj].x - me.x, ry = cjA[jj].y - me.y, rz = cjA[jj].z - me.z;
            float h = F1v + f2A[jj];
            h = fmaf(rw0, rx, h); h = fmaf(rw1, ry, h); h = fmaf(rw2, rz, h);
            float v = fvA[jj];
            v = fmaf(rw3, rx, v); v = fmaf(rw4, ry, v); v = fmaf(rw5, rz, v);
            sh += h; sh2 = fmaf(h, h, sh2);
            sv += v; sv2 = fmaf(v, v, sv2);
        }
    }
    float* bucket = ph2 + (size_t)(blockIdx.x & 255) * 256;
    atomicAdd(&bucket[lane], sh);
    atomicAdd(&bucket[64 + lane], sh2);
    atomicAdd(&bucket[128 + lane], sv);
    atomicAdd(&bucket[192 + lane], sv2);
}

// Reduce PH2[256][256] -> stats[0..255]. 8 blocks; 8 atomics/addr.
__global__ __launch_bounds__(256) void k_red1(
    const float* __restrict__ ph2, float* __restrict__ stats)
{
    int t = threadIdx.x, p = blockIdx.x;
    float acc = 0.f;
    for (int i = 0; i < 32; i++)
        acc += ph2[(size_t)(p * 32 + i) * 256 + t];
    atomicAdd(&stats[t], acc);
}

// Attention + fused Wo matvec + o-stats. SORTED space, XCD-swizzled.
// Per-wave LDS row for the matvec (wave-local, no barrier); opre written
// directly in ORIGINAL layout; o-stats into PO2 buckets (128 RMW/addr).
__global__ __launch_bounds__(256) void k_attn(
    const float4* __restrict__ sx4, const int* __restrict__ sid,
    const int* __restrict__ idx,
    const float* __restrict__ F1, const float* __restrict__ F2, const float* __restrict__ FV,
    const float* __restrict__ relw, const float* __restrict__ stats,
    const float* __restrict__ g1, const float* __restrict__ be1,
    const float* __restrict__ W2, const float* __restrict__ b2,
    const float* __restrict__ gv, const float* __restrict__ bev,
    const float* __restrict__ pwoT, const float* __restrict__ bo,
    float* __restrict__ opre, float* __restrict__ po2)
{
    __shared__ float lds_out[4][64];
    int t = threadIdx.x;
    int lane = t & 63;
    int wl = t >> 6;
    int bx = blockIdx.x;                      // 8192 blocks
    int vb = (bx & 7) * 1024 + (bx >> 3);     // XCD-aware swizzle
    int gq = vb * 4 + wl;                     // sorted-global query
    const float invM = 1.f / 524288.f;
    float hm = stats[lane] * invM, hq = stats[64 + lane] * invM;
    float s1 = g1[lane] * rsqrtf(hq - hm * hm + EPSBN);
    float t1 = be1[lane] - s1 * hm;
    float vm = stats[128 + lane] * invM, vq = stats[192 + lane] * invM;
    float sv = gv[lane] * rsqrtf(vq - vm * vm + EPSBN);
    float tv = bev[lane] - sv * vm;
    float rw0 = relw[0 * 64 + lane], rw1 = relw[1 * 64 + lane], rw2 = relw[2 * 64 + lane];
    float rw3 = relw[3 * 64 + lane], rw4 = relw[4 * 64 + lane], rw5 = relw[5 * 64 + lane];
    float w2v = W2[lane];
    float b2v = b2[0];
    float bov = bo[lane];

    int b = __builtin_amdgcn_readfirstlane(gq >> 13);
    const float4* sb = sx4 + ((size_t)b << 13);
    float4 me = sb[gq & 8191];
    float F1v = F1[(size_t)gq * 64 + lane];
    int orig = (b << 13) + sid[gq];           // wave-uniform scalar
    const int* ip = idx + (size_t)gq * 16;
    float ek[16], vk[16];
#pragma unroll
    for (int kb = 0; kb < 2; kb++) {
        float4 cjA[8]; float f2A[8], fvA[8];
#pragma unroll
        for (int jj = 0; jj < 8; jj++) {
            int gl = ip[kb * 8 + jj];
            cjA[jj] = sb[gl];
            size_t go = (size_t)((b << 13) + gl) * 64 + lane;
            f2A[jj] = F2[go];
            fvA[jj] = FV[go];
        }
#pragma unroll
        for (int jj = 0; jj < 8; jj++) {
            int k = kb * 8 + jj;
            float rx = cjA[jj].x - me.x, ry = cjA[jj].y - me.y, rz = cjA[jj].z - me.z;
            float h = F1v + f2A[jj];
            h = fmaf(rw0, rx, h); h = fmaf(rw1, ry, h); h = fmaf(rw2, rz, h);
            float a = fmaxf(fmaf(s1, h, t1), 0.f);
            float v = fvA[jj];
            v = fmaf(rw3, rx, v); v = fmaf(rw4, ry, v); v = fmaf(rw5, rz, v);
            vk[k] = fmaxf(fmaf(sv, v, tv), 0.f);
            float lg = w2v * a;
#pragma unroll
            for (int off = 32; off >= 1; off >>= 1) lg += __shfl_xor(lg, off, 64);
            ek[k] = lg + b2v;
        }
    }
    float mx = ek[0];
#pragma unroll
    for (int k = 1; k < 16; k++) mx = fmaxf(mx, ek[k]);
    float ssum = 0.f;
#pragma unroll
    for (int k = 0; k < 16; k++) { float e = __expf(ek[k] - mx); ek[k] = e; ssum += e; }
    float acc = 0.f;
#pragma unroll
    for (int k = 0; k < 16; k++) acc = fmaf(ek[k], vk[k], acc);
    float ov = acc / ssum;

    // fused Wo matvec: wave-local LDS row (write->read same wave, no barrier)
    lds_out[wl][lane] = ov;
    float op = bov;
    for (int c = 0; c < 64; c++)
        op = fmaf(pwoT[c * 64 + lane], lds_out[wl][c], op);
    opre[(size_t)orig * 64 + lane] = op;

    float* bucket = po2 + (size_t)(bx & 255) * 128;
    atomicAdd(&bucket[lane], op);
    atomicAdd(&bucket[64 + lane], op * op);
}

// Reduce PO2[256][128] -> stats[256..383]. 8 blocks; 8 atomics/addr.
__global__ __launch_bounds__(256) void k_red2(
    const float* __restrict__ po2, float* __restrict__ stats)
{
    int t = threadIdx.x, p = blockIdx.x;
    if (t < 128) {
        float acc = 0.f;
        for (int i = 0; i < 32; i++)
            acc += po2[(size_t)(p * 32 + i) * 128 + t];
        atomicAdd(&stats[256 + t], acc);
    }
}

// Final: BN(o)+relu + residual feats, transpose [B,N,C]->[B,C,N]
__global__ __launch_bounds__(256) void k_final(
    const float* __restrict__ opre, const float* __restrict__ stats,
    const float* __restrict__ go, const float* __restrict__ beo,
    const float* __restrict__ feats, float* __restrict__ out)
{
    __shared__ float tile[64][65];
    int t = threadIdx.x;
    int blk = blockIdx.x;
    int b = blk >> 7, n0 = (blk & 127) << 6;
#pragma unroll
    for (int i = 0; i < 16; i++) {
        int e = t + i * 256;
        int r = e >> 6, c = e & 63;
        tile[r][c] = opre[((size_t)((b << 13) + n0 + r)) * 64 + c];
    }
    __syncthreads();
    const float invM = 1.f / 32768.f;
    int lane = t & 63, wv = t >> 6;
#pragma unroll
    for (int i = 0; i < 16; i++) {
        int c = wv * 16 + i;
        float om = stats[256 + c] * invM, oq = stats[320 + c] * invM;
        float so = go[c] * rsqrtf(oq - om * om + EPSBN);
        float to = beo[c] - so * om;
        float val = fmaxf(fmaf(so, tile[lane][c], to), 0.f);
        size_t oix = ((size_t)b * 64 + c) * NN + n0 + lane;
        out[oix] = val + feats[oix];
    }
}

extern "C" void kernel_launch(void* const* d_in, const int* in_sizes, int n_in,
                              void* d_out, int out_size, void* d_ws, size_t ws_size,
                              hipStream_t stream)
{
    const float* xyz  = (const float*)d_in[0];
    const float* feats= (const float*)d_in[1];
    const float* W1   = (const float*)d_in[2];
    const float* b1   = (const float*)d_in[3];
    const float* g1   = (const float*)d_in[4];
    const float* be1  = (const float*)d_in[5];
    const float* W2   = (const float*)d_in[6];
    const float* b2   = (const float*)d_in[7];
    const float* Wv   = (const float*)d_in[8];
    const float* bv   = (const float*)d_in[9];
    const float* gv   = (const float*)d_in[10];
    const float* bev  = (const float*)d_in[11];
    const float* Wo   = (const float*)d_in[12];
    const float* bo   = (const float*)d_in[13];
    const float* go   = (const float*)d_in[14];
    const float* beo  = (const float*)d_in[15];

    float* ws = (float*)d_ws;
    float* xyzw  = ws + OFF_XYZW;
    float* pw1aT = ws + OFF_PW1AT;
    float* pw1bT = ws + OFF_PW1BT;
    float* pwvaT = ws + OFF_PWVAT;
    float* pwoT  = ws + OFF_PWOT;
    float* relw  = ws + OFF_RELW;
    float* stats = ws + OFF_STATS;
    int*   idx   = (int*)(ws + OFF_IDX);
    float* opre  = ws + OFF_OPRE;
    float4* sx4  = (float4*)(ws + OFF_SX4);
    int*   sid   = (int*)(ws + OFF_SID);
    int*   hist  = (int*)(ws + OFF_HIST);
    float4* bbmn = (float4*)(ws + OFF_BB);
    float4* bbmx = (float4*)(ws + OFF_BB + 2048);
    int*   rank  = (int*)(ws + OFF_RANK);
    float* ph2   = ws + OFF_PH;
    float* po2   = ws + OFF_PO;
    float* F1    = ws + OFF_F1;
    float* F2    = ws + OFF_F2;
    float* FV    = ws + OFF_FV;

    hipMemsetAsync(hist, 0, BB * NCELL * sizeof(int), stream);
    hipMemsetAsync(ph2, 0, (65536 + 32768) * sizeof(float), stream);  // PH2+PO2 contiguous
    k_prep<<<129, 256, 0, stream>>>(xyz, W1, Wv, Wo, xyzw, hist,
                                    pw1aT, pw1bT, pwvaT, pwoT, relw, stats);
    k_scan<<<4, 256, 0, stream>>>(hist);
    k_scatter<<<128, 256, 0, stream>>>((const float4*)xyzw, hist, sx4, sid, rank);
    k_bbox<<<128, 256, 0, stream>>>((const float4*)sx4, bbmn, bbmx);
    k_F<<<512, 256, 0, stream>>>(feats, b1, bv, pw1aT, pw1bT, pwvaT, rank, F1, F2, FV);
    k_knn<<<NPTS / 2, 128, 0, stream>>>((const float4*)sx4, sid, bbmn, bbmx,
                                        F1, F2, FV, relw, idx, ph2);
    k_red1<<<8, 256, 0, stream>>>(ph2, stats);
    k_attn<<<8192, 256, 0, stream>>>((const float4*)sx4, sid, idx, F1, F2, FV, relw, stats,
                                     g1, be1, W2, b2, gv, bev, pwoT, bo, opre, po2);
    k_red2<<<8, 256, 0, stream>>>(po2, stats);
    k_final<<<512, 256, 0, stream>>>(opre, stats, go, beo, feats, (float*)d_out);
}